// Round 5
// baseline (2883.369 us; speedup 1.0000x reference)
//
#include <hip/hip_runtime.h>
#include <math.h>

#define N_NODES 16384
#define N_EDGES 524288
#define N_GRAPHS 64
#define HID 128
#define FILT 128
#define NG 51
#define NL 6
#define RPB 16       // rows per block in edge kernel
#define TROWS 2048   // filter-table resolution
#define DMAX 8.66025404f          // 5*sqrt(3), max possible distance
#define DSTEP (DMAX / (TROWS - 1))
#define INV_DSTEP ((TROWS - 1) / DMAX)
#define SWZ(k) (((k) >> 1) & 12)

__device__ __forceinline__ float ssp(float x) {
    float sp = (x > 20.0f) ? x : log1pf(__expf(x));
    return sp - 0.6931471805599453f;
}

__global__ void k_embed(const int* __restrict__ z, const float* __restrict__ emb,
                        float* __restrict__ h) {
    int i = blockIdx.x * blockDim.x + threadIdx.x;
    int n = i >> 7, c = i & 127;
    h[i] = emb[z[n] * HID + c];
}

__global__ void k_hist(const int* __restrict__ ei, int* __restrict__ cnt) {
    int e = blockIdx.x * blockDim.x + threadIdx.x;
    if (e < N_EDGES) atomicAdd(&cnt[ei[e]], 1);
}

__global__ __launch_bounds__(1024) void k_scan(const int* __restrict__ cnt,
                                               int* __restrict__ rowptr,
                                               int* __restrict__ wo) {
    __shared__ int sums[1024];
    int t = threadIdx.x;
    int loc[16];
    int s = 0;
    #pragma unroll
    for (int i = 0; i < 16; ++i) { loc[i] = cnt[t * 16 + i]; s += loc[i]; }
    sums[t] = s;
    __syncthreads();
    for (int off = 1; off < 1024; off <<= 1) {
        int v = sums[t];
        int u = (t >= off) ? sums[t - off] : 0;
        __syncthreads();
        sums[t] = v + u;
        __syncthreads();
    }
    int ex = sums[t] - s;
    #pragma unroll
    for (int i = 0; i < 16; ++i) {
        rowptr[t * 16 + i] = ex;
        wo[t * 16 + i] = ex;
        ex += loc[i];
    }
    if (t == 1023) rowptr[16384] = ex;
}

// scatter into CSR order with packed meta: x = col | (localrow<<20), y = ew bits
__global__ void k_scatter(const int* __restrict__ ei, const float* __restrict__ pos,
                          int* __restrict__ wo, int2* __restrict__ meta) {
    int e = blockIdx.x * blockDim.x + threadIdx.x;
    if (e >= N_EDGES) return;
    int r = ei[e], c = ei[N_EDGES + e];
    int p = atomicAdd(&wo[r], 1);
    float dx = pos[r * 3 + 0] - pos[c * 3 + 0];
    float dy = pos[r * 3 + 1] - pos[c * 3 + 1];
    float dz = pos[r * 3 + 2] - pos[c * 3 + 2];
    float ew = sqrtf(dx * dx + dy * dy + dz * dz);
    meta[p] = make_int2(c | ((r & (RPB - 1)) << 20), __float_as_int(ew));
}

// Filter tables: ftab[layer][i][c] = (ssp(gauss(d_i)@W1+b1)@W2+b2)[c] * C(d_i)
__global__ __launch_bounds__(512) void k_tab(
    const float* __restrict__ mlp1_w, const float* __restrict__ mlp1_b,
    const float* __restrict__ mlp2_w, const float* __restrict__ mlp2_b,
    float* __restrict__ ftab)
{
    const int layer = blockIdx.x >> 5;
    const int tile  = blockIdx.x & 31;
    const float* W1 = mlp1_w + (size_t)layer * NG * FILT;
    const float* B1 = mlp1_b + (size_t)layer * FILT;
    const float* W2 = mlp2_w + (size_t)layer * FILT * FILT;
    const float* B2 = mlp2_b + (size_t)layer * FILT;
    float* out = ftab + (size_t)layer * TROWS * FILT + (size_t)tile * 64 * FILT;
    __shared__ float buf[FILT * 64];
    const int tid = threadIdx.x;
    const int e0 = (tid & 15) * 4;
    const int c0 = (tid >> 4) * 4;
    for (int idx = tid; idx < NG * 64; idx += 512) {
        int k = idx >> 6, e = idx & 63;
        float d = (float)(tile * 64 + e) * DSTEP;
        float dd = d - 0.2f * (float)k;
        buf[idx] = __expf(-12.5f * dd * dd);
    }
    __syncthreads();
    float acc[4][4];
    #pragma unroll
    for (int i = 0; i < 4; ++i)
        #pragma unroll
        for (int j = 0; j < 4; ++j) acc[i][j] = B1[c0 + j];
    for (int k = 0; k < NG; ++k) {
        float4 a = *(float4*)&buf[k * 64 + e0];
        float4 b = *(const float4*)&W1[k * FILT + c0];
        #pragma unroll
        for (int i = 0; i < 4; ++i)
            #pragma unroll
            for (int j = 0; j < 4; ++j)
                acc[i][j] += ((float*)&a)[i] * ((float*)&b)[j];
    }
    __syncthreads();
    #pragma unroll
    for (int j = 0; j < 4; ++j) {
        float4 w;
        ((float*)&w)[0] = ssp(acc[0][j]);
        ((float*)&w)[1] = ssp(acc[1][j]);
        ((float*)&w)[2] = ssp(acc[2][j]);
        ((float*)&w)[3] = ssp(acc[3][j]);
        *(float4*)&buf[(c0 + j) * 64 + e0] = w;
    }
    __syncthreads();
    float acc2[4][4];
    #pragma unroll
    for (int i = 0; i < 4; ++i)
        #pragma unroll
        for (int j = 0; j < 4; ++j) acc2[i][j] = B2[c0 + j];
    for (int k = 0; k < FILT; ++k) {
        float4 a = *(float4*)&buf[k * 64 + e0];
        float4 b = *(const float4*)&W2[k * FILT + c0];
        #pragma unroll
        for (int i = 0; i < 4; ++i)
            #pragma unroll
            for (int j = 0; j < 4; ++j)
                acc2[i][j] += ((float*)&a)[i] * ((float*)&b)[j];
    }
    #pragma unroll
    for (int i = 0; i < 4; ++i) {
        int r = tile * 64 + e0 + i;
        float d = (float)r * DSTEP;
        float C = 0.5f * (__cosf(d * 0.31415926535f) + 1.0f);
        #pragma unroll
        for (int j = 0; j < 4; ++j)
            out[(e0 + i) * FILT + c0 + j] = acc2[i][j] * C;
    }
}

// Per-edge lerp + modulate + LDS aggregation, 4-edge ILP batch.
// Block owns rows [r0, r0+RPB). 512 threads = 16 edge-groups x 32 ch-groups.
__global__ __launch_bounds__(512, 4) void k_edge2(
    const int2* __restrict__ meta, const int* __restrict__ rowptr,
    const float* __restrict__ xh, const float* __restrict__ tab,
    float* __restrict__ agg)
{
    __shared__ float aggs[RPB * FILT];   // 8 KB
    const int tid = threadIdx.x;
    for (int i = tid; i < RPB * FILT; i += 512) aggs[i] = 0.f;
    const int c0 = (tid & 31) * 4;
    const int eg = tid >> 5;             // 0..15
    const int r0 = blockIdx.x * RPB;
    const int estart = rowptr[r0], eend = rowptr[r0 + RPB];
    __syncthreads();
    for (int eb = estart; eb < eend; eb += 64) {
        int2 m[4];
        float sc[4];
        #pragma unroll
        for (int u = 0; u < 4; ++u) {
            int e = eb + u * 16 + eg;
            int ec = min(e, eend - 1);
            m[u] = meta[ec];
            sc[u] = (e < eend) ? 1.0f : 0.0f;
        }
        float4 t0[4], t1[4], xv[4];
        float f[4];
        int lr[4];
        #pragma unroll
        for (int u = 0; u < 4; ++u) {
            int col = m[u].x & 0xFFFFF;
            lr[u] = m[u].x >> 20;
            float d = __int_as_float(m[u].y);
            float uu = d * INV_DSTEP;
            int i0 = min((int)uu, TROWS - 2);
            f[u] = uu - (float)i0;
            t0[u] = *(const float4*)&tab[(size_t)i0 * FILT + c0];
            t1[u] = *(const float4*)&tab[(size_t)(i0 + 1) * FILT + c0];
            xv[u] = *(const float4*)&xh[(size_t)col * FILT + c0];
        }
        #pragma unroll
        for (int u = 0; u < 4; ++u) {
            #pragma unroll
            for (int j = 0; j < 4; ++j) {
                float w = fmaf(f[u], ((float*)&t1[u])[j] - ((float*)&t0[u])[j],
                               ((float*)&t0[u])[j]);
                atomicAdd(&aggs[lr[u] * FILT + c0 + j],
                          w * ((float*)&xv[u])[j] * sc[u]);
            }
        }
    }
    __syncthreads();
    for (int i = tid; i < RPB * FILT; i += 512)
        agg[r0 * FILT + i] = aggs[i];
}

// Single GEMM: Y = X @ W  (64-node tile, X^T staged in LDS, W from global)
__global__ __launch_bounds__(512, 4) void k_xh2(const float* __restrict__ X,
                                                const float* __restrict__ W,
                                                float* __restrict__ Y) {
    __shared__ float buf[128 * 68];   // 34816 B
    const int tid = threadIdx.x;
    const int n2 = (tid >> 4) * 2;
    const int c0 = (tid & 15) * 8;
    const int n0 = blockIdx.x * 64;
    for (int fi = tid; fi < 64 * 32; fi += 512) {
        int node = fi >> 5, kq = fi & 31;
        float4 v = *(const float4*)&X[(size_t)(n0 + node) * 128 + kq * 4];
        int nn = node ^ ((kq << 1) & 12);
        buf[(4 * kq + 0) * 68 + nn] = v.x;
        buf[(4 * kq + 1) * 68 + nn] = v.y;
        buf[(4 * kq + 2) * 68 + nn] = v.z;
        buf[(4 * kq + 3) * 68 + nn] = v.w;
    }
    __syncthreads();
    float acc[2][8];
    #pragma unroll
    for (int i = 0; i < 2; ++i)
        #pragma unroll
        for (int j = 0; j < 8; ++j) acc[i][j] = 0.f;
    #pragma unroll 2
    for (int k = 0; k < 128; ++k) {
        float2 a = *(float2*)&buf[k * 68 + (n2 ^ SWZ(k))];
        float4 b0 = *(const float4*)&W[k * 128 + c0];
        float4 b1 = *(const float4*)&W[k * 128 + c0 + 4];
        #pragma unroll
        for (int i = 0; i < 2; ++i) {
            float av = ((float*)&a)[i];
            acc[i][0] = fmaf(av, b0.x, acc[i][0]);
            acc[i][1] = fmaf(av, b0.y, acc[i][1]);
            acc[i][2] = fmaf(av, b0.z, acc[i][2]);
            acc[i][3] = fmaf(av, b0.w, acc[i][3]);
            acc[i][4] = fmaf(av, b1.x, acc[i][4]);
            acc[i][5] = fmaf(av, b1.y, acc[i][5]);
            acc[i][6] = fmaf(av, b1.z, acc[i][6]);
            acc[i][7] = fmaf(av, b1.w, acc[i][7]);
        }
    }
    #pragma unroll
    for (int i = 0; i < 2; ++i) {
        size_t ro = (size_t)(n0 + n2 + i) * 128;
        *(float4*)&Y[ro + c0]     = make_float4(acc[i][0], acc[i][1], acc[i][2], acc[i][3]);
        *(float4*)&Y[ro + c0 + 4] = make_float4(acc[i][4], acc[i][5], acc[i][6], acc[i][7]);
    }
}

// Fused node update: t = ssp(X@W1+B1); out = t@W2+B2 (+Hin); Hout = out;
// optionally XHout = out @ W3 (next layer's cl1).
template<bool RESID, bool G3>
__global__ __launch_bounds__(512, 4) void k_node2(
    const float* __restrict__ X,
    const float* __restrict__ W1, const float* __restrict__ B1,
    const float* __restrict__ W2, const float* __restrict__ B2,
    const float* __restrict__ Hin, float* __restrict__ Hout,
    const float* __restrict__ W3, float* __restrict__ XHout)
{
    __shared__ float buf[128 * 68];
    const int tid = threadIdx.x;
    const int n2 = (tid >> 4) * 2;
    const int c0 = (tid & 15) * 8;
    const int n0 = blockIdx.x * 64;
    for (int fi = tid; fi < 64 * 32; fi += 512) {
        int node = fi >> 5, kq = fi & 31;
        float4 v = *(const float4*)&X[(size_t)(n0 + node) * 128 + kq * 4];
        int nn = node ^ ((kq << 1) & 12);
        buf[(4 * kq + 0) * 68 + nn] = v.x;
        buf[(4 * kq + 1) * 68 + nn] = v.y;
        buf[(4 * kq + 2) * 68 + nn] = v.z;
        buf[(4 * kq + 3) * 68 + nn] = v.w;
    }
    __syncthreads();
    float acc[2][8];
    {
        float4 bb0 = *(const float4*)&B1[c0];
        float4 bb1 = *(const float4*)&B1[c0 + 4];
        #pragma unroll
        for (int i = 0; i < 2; ++i) {
            acc[i][0] = bb0.x; acc[i][1] = bb0.y; acc[i][2] = bb0.z; acc[i][3] = bb0.w;
            acc[i][4] = bb1.x; acc[i][5] = bb1.y; acc[i][6] = bb1.z; acc[i][7] = bb1.w;
        }
    }
    #pragma unroll 2
    for (int k = 0; k < 128; ++k) {
        float2 a = *(float2*)&buf[k * 68 + (n2 ^ SWZ(k))];
        float4 b0 = *(const float4*)&W1[k * 128 + c0];
        float4 b1 = *(const float4*)&W1[k * 128 + c0 + 4];
        #pragma unroll
        for (int i = 0; i < 2; ++i) {
            float av = ((float*)&a)[i];
            acc[i][0] = fmaf(av, b0.x, acc[i][0]);
            acc[i][1] = fmaf(av, b0.y, acc[i][1]);
            acc[i][2] = fmaf(av, b0.z, acc[i][2]);
            acc[i][3] = fmaf(av, b0.w, acc[i][3]);
            acc[i][4] = fmaf(av, b1.x, acc[i][4]);
            acc[i][5] = fmaf(av, b1.y, acc[i][5]);
            acc[i][6] = fmaf(av, b1.z, acc[i][6]);
            acc[i][7] = fmaf(av, b1.w, acc[i][7]);
        }
    }
    __syncthreads();
    #pragma unroll
    for (int j = 0; j < 8; ++j) {
        int kk = c0 + j;
        int sw = SWZ(kk);
        buf[kk * 68 + (n2 ^ sw)]       = ssp(acc[0][j]);
        buf[kk * 68 + ((n2 + 1) ^ sw)] = ssp(acc[1][j]);
    }
    __syncthreads();
    float acc2[2][8];
    {
        float4 bb0 = *(const float4*)&B2[c0];
        float4 bb1 = *(const float4*)&B2[c0 + 4];
        #pragma unroll
        for (int i = 0; i < 2; ++i) {
            acc2[i][0] = bb0.x; acc2[i][1] = bb0.y; acc2[i][2] = bb0.z; acc2[i][3] = bb0.w;
            acc2[i][4] = bb1.x; acc2[i][5] = bb1.y; acc2[i][6] = bb1.z; acc2[i][7] = bb1.w;
        }
    }
    #pragma unroll 2
    for (int k = 0; k < 128; ++k) {
        float2 a = *(float2*)&buf[k * 68 + (n2 ^ SWZ(k))];
        float4 b0 = *(const float4*)&W2[k * 128 + c0];
        float4 b1 = *(const float4*)&W2[k * 128 + c0 + 4];
        #pragma unroll
        for (int i = 0; i < 2; ++i) {
            float av = ((float*)&a)[i];
            acc2[i][0] = fmaf(av, b0.x, acc2[i][0]);
            acc2[i][1] = fmaf(av, b0.y, acc2[i][1]);
            acc2[i][2] = fmaf(av, b0.z, acc2[i][2]);
            acc2[i][3] = fmaf(av, b0.w, acc2[i][3]);
            acc2[i][4] = fmaf(av, b1.x, acc2[i][4]);
            acc2[i][5] = fmaf(av, b1.y, acc2[i][5]);
            acc2[i][6] = fmaf(av, b1.z, acc2[i][6]);
            acc2[i][7] = fmaf(av, b1.w, acc2[i][7]);
        }
    }
    #pragma unroll
    for (int i = 0; i < 2; ++i) {
        size_t ro = (size_t)(n0 + n2 + i) * 128;
        if (RESID) {
            float4 h0 = *(const float4*)&Hin[ro + c0];
            float4 h1 = *(const float4*)&Hin[ro + c0 + 4];
            acc2[i][0] += h0.x; acc2[i][1] += h0.y; acc2[i][2] += h0.z; acc2[i][3] += h0.w;
            acc2[i][4] += h1.x; acc2[i][5] += h1.y; acc2[i][6] += h1.z; acc2[i][7] += h1.w;
        }
        *(float4*)&Hout[ro + c0]     = make_float4(acc2[i][0], acc2[i][1], acc2[i][2], acc2[i][3]);
        *(float4*)&Hout[ro + c0 + 4] = make_float4(acc2[i][4], acc2[i][5], acc2[i][6], acc2[i][7]);
    }
    if (G3) {
        __syncthreads();
        #pragma unroll
        for (int j = 0; j < 8; ++j) {
            int kk = c0 + j;
            int sw = SWZ(kk);
            buf[kk * 68 + (n2 ^ sw)]       = acc2[0][j];
            buf[kk * 68 + ((n2 + 1) ^ sw)] = acc2[1][j];
        }
        __syncthreads();
        float acc3[2][8];
        #pragma unroll
        for (int i = 0; i < 2; ++i)
            #pragma unroll
            for (int j = 0; j < 8; ++j) acc3[i][j] = 0.f;
        #pragma unroll 2
        for (int k = 0; k < 128; ++k) {
            float2 a = *(float2*)&buf[k * 68 + (n2 ^ SWZ(k))];
            float4 b0 = *(const float4*)&W3[k * 128 + c0];
            float4 b1 = *(const float4*)&W3[k * 128 + c0 + 4];
            #pragma unroll
            for (int i = 0; i < 2; ++i) {
                float av = ((float*)&a)[i];
                acc3[i][0] = fmaf(av, b0.x, acc3[i][0]);
                acc3[i][1] = fmaf(av, b0.y, acc3[i][1]);
                acc3[i][2] = fmaf(av, b0.z, acc3[i][2]);
                acc3[i][3] = fmaf(av, b0.w, acc3[i][3]);
                acc3[i][4] = fmaf(av, b1.x, acc3[i][4]);
                acc3[i][5] = fmaf(av, b1.y, acc3[i][5]);
                acc3[i][6] = fmaf(av, b1.z, acc3[i][6]);
                acc3[i][7] = fmaf(av, b1.w, acc3[i][7]);
            }
        }
        #pragma unroll
        for (int i = 0; i < 2; ++i) {
            size_t ro = (size_t)(n0 + n2 + i) * 128;
            *(float4*)&XHout[ro + c0]     = make_float4(acc3[i][0], acc3[i][1], acc3[i][2], acc3[i][3]);
            *(float4*)&XHout[ro + c0 + 4] = make_float4(acc3[i][4], acc3[i][5], acc3[i][6], acc3[i][7]);
        }
    }
}

__global__ void k_pool(const float* __restrict__ hout, const int* __restrict__ batch,
                       float* __restrict__ out) {
    int g = blockIdx.x;
    int c = threadIdx.x;
    int a = 0, b = N_NODES;
    while (a < b) { int m = (a + b) >> 1; if (batch[m] < g) a = m + 1; else b = m; }
    int lo = a;
    b = N_NODES;
    while (a < b) { int m = (a + b) >> 1; if (batch[m] < g + 1) a = m + 1; else b = m; }
    int hi = a;
    float s = 0.f;
    for (int n = lo; n < hi; ++n) s += hout[n * HID + c];
    int cnt = hi - lo;
    out[g * HID + c] = s / fmaxf((float)cnt, 1.0f);
}

extern "C" void kernel_launch(void* const* d_in, const int* in_sizes, int n_in,
                              void* d_out, int out_size, void* d_ws, size_t ws_size,
                              hipStream_t stream) {
    const int*   z       = (const int*)  d_in[0];
    const float* pos     = (const float*)d_in[1];
    const int*   batch   = (const int*)  d_in[2];
    const int*   ei      = (const int*)  d_in[3];
    const float* emb     = (const float*)d_in[4];
    const float* mlp1_w  = (const float*)d_in[5];
    const float* mlp1_b  = (const float*)d_in[6];
    const float* mlp2_w  = (const float*)d_in[7];
    const float* mlp2_b  = (const float*)d_in[8];
    const float* cl1_w   = (const float*)d_in[9];
    const float* cl2_w   = (const float*)d_in[10];
    const float* cl2_b   = (const float*)d_in[11];
    const float* lin_w   = (const float*)d_in[12];
    const float* lin_b   = (const float*)d_in[13];
    const float* out1_w  = (const float*)d_in[14];
    const float* out1_b  = (const float*)d_in[15];
    const float* out2_w  = (const float*)d_in[16];
    const float* out2_b  = (const float*)d_in[17];

    float* ws     = (float*)d_ws;
    float* h      = ws;
    float* xh     = h    + (size_t)N_NODES * HID;
    float* agg    = xh   + (size_t)N_NODES * HID;
    int2*  meta   = (int2*)(agg + (size_t)N_NODES * HID);
    int*   cnt    = (int*)(meta + N_EDGES);
    int*   rowptr = cnt + N_NODES;
    int*   wo     = rowptr + N_NODES + 1;
    float* ftab   = (float*)(wo + N_NODES);   // NL*TROWS*FILT

    hipMemsetAsync(cnt, 0, N_NODES * sizeof(int), stream);
    k_embed<<<N_NODES * HID / 256, 256, 0, stream>>>(z, emb, h);
    k_hist<<<N_EDGES / 256, 256, 0, stream>>>(ei, cnt);
    k_scan<<<1, 1024, 0, stream>>>(cnt, rowptr, wo);
    k_scatter<<<N_EDGES / 256, 256, 0, stream>>>(ei, pos, wo, meta);
    k_tab<<<NL * 32, 512, 0, stream>>>(mlp1_w, mlp1_b, mlp2_w, mlp2_b, ftab);

    k_xh2<<<N_NODES / 64, 512, 0, stream>>>(h, cl1_w, xh);
    for (int i = 0; i < NL; ++i) {
        k_edge2<<<N_NODES / RPB, 512, 0, stream>>>(
            meta, rowptr, xh, ftab + (size_t)i * TROWS * FILT, agg);
        if (i < NL - 1) {
            k_node2<true, true><<<N_NODES / 64, 512, 0, stream>>>(
                agg, cl2_w + (size_t)i * FILT * HID, cl2_b + (size_t)i * HID,
                lin_w + (size_t)i * HID * HID, lin_b + (size_t)i * HID,
                h, h, cl1_w + (size_t)(i + 1) * HID * FILT, xh);
        } else {
            k_node2<true, false><<<N_NODES / 64, 512, 0, stream>>>(
                agg, cl2_w + (size_t)i * FILT * HID, cl2_b + (size_t)i * HID,
                lin_w + (size_t)i * HID * HID, lin_b + (size_t)i * HID,
                h, h, nullptr, nullptr);
        }
    }
    k_node2<false, false><<<N_NODES / 64, 512, 0, stream>>>(
        h, out1_w, out1_b, out2_w, out2_b, nullptr, xh, nullptr, nullptr);
    k_pool<<<N_GRAPHS, HID, 0, stream>>>(xh, batch, (float*)d_out);
}

// Round 6
// 1063.160 us; speedup vs baseline: 2.7121x; 2.7121x over previous
//
#include <hip/hip_runtime.h>
#include <math.h>

#define N_NODES 16384
#define N_EDGES 524288
#define N_GRAPHS 64
#define HID 128
#define FILT 128
#define NG 51
#define NL 6
#define TROWS 2048   // filter-table resolution
#define DMAX 8.66025404f          // 5*sqrt(3), max possible distance
#define DSTEP (DMAX / (TROWS - 1))
#define INV_DSTEP ((TROWS - 1) / DMAX)
#define SWZ(k) (((k) >> 1) & 12)
#define EUNROLL 8

__device__ __forceinline__ float ssp(float x) {
    float sp = (x > 20.0f) ? x : log1pf(__expf(x));
    return sp - 0.6931471805599453f;
}

__global__ void k_embed(const int* __restrict__ z, const float* __restrict__ emb,
                        float* __restrict__ h) {
    int i = blockIdx.x * blockDim.x + threadIdx.x;
    int n = i >> 7, c = i & 127;
    h[i] = emb[z[n] * HID + c];
}

__global__ void k_hist(const int* __restrict__ ei, int* __restrict__ cnt) {
    int e = blockIdx.x * blockDim.x + threadIdx.x;
    if (e < N_EDGES) atomicAdd(&cnt[ei[e]], 1);
}

__global__ __launch_bounds__(1024) void k_scan(const int* __restrict__ cnt,
                                               int* __restrict__ rowptr,
                                               int* __restrict__ wo) {
    __shared__ int sums[1024];
    int t = threadIdx.x;
    int loc[16];
    int s = 0;
    #pragma unroll
    for (int i = 0; i < 16; ++i) { loc[i] = cnt[t * 16 + i]; s += loc[i]; }
    sums[t] = s;
    __syncthreads();
    for (int off = 1; off < 1024; off <<= 1) {
        int v = sums[t];
        int u = (t >= off) ? sums[t - off] : 0;
        __syncthreads();
        sums[t] = v + u;
        __syncthreads();
    }
    int ex = sums[t] - s;
    #pragma unroll
    for (int i = 0; i < 16; ++i) {
        rowptr[t * 16 + i] = ex;
        wo[t * 16 + i] = ex;
        ex += loc[i];
    }
    if (t == 1023) rowptr[16384] = ex;
}

// scatter into CSR order: meta.x = col, meta.y = ew bits
__global__ void k_scatter(const int* __restrict__ ei, const float* __restrict__ pos,
                          int* __restrict__ wo, int2* __restrict__ meta) {
    int e = blockIdx.x * blockDim.x + threadIdx.x;
    if (e >= N_EDGES) return;
    int r = ei[e], c = ei[N_EDGES + e];
    int p = atomicAdd(&wo[r], 1);
    float dx = pos[r * 3 + 0] - pos[c * 3 + 0];
    float dy = pos[r * 3 + 1] - pos[c * 3 + 1];
    float dz = pos[r * 3 + 2] - pos[c * 3 + 2];
    float ew = sqrtf(dx * dx + dy * dy + dz * dz);
    meta[p] = make_int2(c, __float_as_int(ew));
}

// Filter tables: ftab[layer][i][c] = (ssp(gauss(d_i)@W1+b1)@W2+b2)[c] * C(d_i)
__global__ __launch_bounds__(512) void k_tab(
    const float* __restrict__ mlp1_w, const float* __restrict__ mlp1_b,
    const float* __restrict__ mlp2_w, const float* __restrict__ mlp2_b,
    float* __restrict__ ftab)
{
    const int layer = blockIdx.x >> 5;
    const int tile  = blockIdx.x & 31;
    const float* W1 = mlp1_w + (size_t)layer * NG * FILT;
    const float* B1 = mlp1_b + (size_t)layer * FILT;
    const float* W2 = mlp2_w + (size_t)layer * FILT * FILT;
    const float* B2 = mlp2_b + (size_t)layer * FILT;
    float* out = ftab + (size_t)layer * TROWS * FILT + (size_t)tile * 64 * FILT;
    __shared__ float buf[FILT * 64];
    const int tid = threadIdx.x;
    const int e0 = (tid & 15) * 4;
    const int c0 = (tid >> 4) * 4;
    for (int idx = tid; idx < NG * 64; idx += 512) {
        int k = idx >> 6, e = idx & 63;
        float d = (float)(tile * 64 + e) * DSTEP;
        float dd = d - 0.2f * (float)k;
        buf[idx] = __expf(-12.5f * dd * dd);
    }
    __syncthreads();
    float acc[4][4];
    #pragma unroll
    for (int i = 0; i < 4; ++i)
        #pragma unroll
        for (int j = 0; j < 4; ++j) acc[i][j] = B1[c0 + j];
    for (int k = 0; k < NG; ++k) {
        float4 a = *(float4*)&buf[k * 64 + e0];
        float4 b = *(const float4*)&W1[k * FILT + c0];
        #pragma unroll
        for (int i = 0; i < 4; ++i)
            #pragma unroll
            for (int j = 0; j < 4; ++j)
                acc[i][j] += ((float*)&a)[i] * ((float*)&b)[j];
    }
    __syncthreads();
    #pragma unroll
    for (int j = 0; j < 4; ++j) {
        float4 w;
        ((float*)&w)[0] = ssp(acc[0][j]);
        ((float*)&w)[1] = ssp(acc[1][j]);
        ((float*)&w)[2] = ssp(acc[2][j]);
        ((float*)&w)[3] = ssp(acc[3][j]);
        *(float4*)&buf[(c0 + j) * 64 + e0] = w;
    }
    __syncthreads();
    float acc2[4][4];
    #pragma unroll
    for (int i = 0; i < 4; ++i)
        #pragma unroll
        for (int j = 0; j < 4; ++j) acc2[i][j] = B2[c0 + j];
    for (int k = 0; k < FILT; ++k) {
        float4 a = *(float4*)&buf[k * 64 + e0];
        float4 b = *(const float4*)&W2[k * FILT + c0];
        #pragma unroll
        for (int i = 0; i < 4; ++i)
            #pragma unroll
            for (int j = 0; j < 4; ++j)
                acc2[i][j] += ((float*)&a)[i] * ((float*)&b)[j];
    }
    #pragma unroll
    for (int i = 0; i < 4; ++i) {
        int r = tile * 64 + e0 + i;
        float d = (float)r * DSTEP;
        float C = 0.5f * (__cosf(d * 0.31415926535f) + 1.0f);
        #pragma unroll
        for (int j = 0; j < 4; ++j)
            out[(e0 + i) * FILT + c0 + j] = acc2[i][j] * C;
    }
}

// Wave-per-row edge aggregation: each wave owns one destination row, lane
// holds 2 channels of the accumulator in registers. No LDS, no atomics.
__global__ __launch_bounds__(256) void k_edge3(
    const int2* __restrict__ meta, const int* __restrict__ rowptr,
    const float* __restrict__ xh, const float* __restrict__ tab,
    float* __restrict__ agg)
{
    const int row = blockIdx.x * 4 + (threadIdx.x >> 6);
    const int c2 = (threadIdx.x & 63) * 2;
    const int es = rowptr[row], ee = rowptr[row + 1];
    float ax = 0.f, ay = 0.f;
    for (int e = es; e < ee; e += EUNROLL) {
        float2 t0[EUNROLL], t1[EUNROLL], xv[EUNROLL];
        float f[EUNROLL], sc[EUNROLL];
        #pragma unroll
        for (int u = 0; u < EUNROLL; ++u) {
            int ec = min(e + u, ee - 1);
            sc[u] = (e + u < ee) ? 1.f : 0.f;
            int2 m = meta[ec];                       // wave-uniform broadcast
            float d = __int_as_float(m.y);
            float uu = d * INV_DSTEP;
            int i0 = min((int)uu, TROWS - 2);
            f[u] = uu - (float)i0;
            t0[u] = *(const float2*)&tab[(size_t)i0 * FILT + c2];
            t1[u] = *(const float2*)&tab[(size_t)(i0 + 1) * FILT + c2];
            xv[u] = *(const float2*)&xh[(size_t)m.x * FILT + c2];
        }
        #pragma unroll
        for (int u = 0; u < EUNROLL; ++u) {
            float wx = fmaf(f[u], t1[u].x - t0[u].x, t0[u].x) * sc[u];
            float wy = fmaf(f[u], t1[u].y - t0[u].y, t0[u].y) * sc[u];
            ax = fmaf(wx, xv[u].x, ax);
            ay = fmaf(wy, xv[u].y, ay);
        }
    }
    *(float2*)&agg[(size_t)row * FILT + c2] = make_float2(ax, ay);
}

// Single GEMM: Y = X @ W  (64-node tile, X^T staged in LDS, W from global)
__global__ __launch_bounds__(512, 4) void k_xh2(const float* __restrict__ X,
                                                const float* __restrict__ W,
                                                float* __restrict__ Y) {
    __shared__ float buf[128 * 68];   // 34816 B
    const int tid = threadIdx.x;
    const int n2 = (tid >> 4) * 2;
    const int c0 = (tid & 15) * 8;
    const int n0 = blockIdx.x * 64;
    for (int fi = tid; fi < 64 * 32; fi += 512) {
        int node = fi >> 5, kq = fi & 31;
        float4 v = *(const float4*)&X[(size_t)(n0 + node) * 128 + kq * 4];
        int nn = node ^ ((kq << 1) & 12);
        buf[(4 * kq + 0) * 68 + nn] = v.x;
        buf[(4 * kq + 1) * 68 + nn] = v.y;
        buf[(4 * kq + 2) * 68 + nn] = v.z;
        buf[(4 * kq + 3) * 68 + nn] = v.w;
    }
    __syncthreads();
    float acc[2][8];
    #pragma unroll
    for (int i = 0; i < 2; ++i)
        #pragma unroll
        for (int j = 0; j < 8; ++j) acc[i][j] = 0.f;
    #pragma unroll 2
    for (int k = 0; k < 128; ++k) {
        float2 a = *(float2*)&buf[k * 68 + (n2 ^ SWZ(k))];
        float4 b0 = *(const float4*)&W[k * 128 + c0];
        float4 b1 = *(const float4*)&W[k * 128 + c0 + 4];
        #pragma unroll
        for (int i = 0; i < 2; ++i) {
            float av = ((float*)&a)[i];
            acc[i][0] = fmaf(av, b0.x, acc[i][0]);
            acc[i][1] = fmaf(av, b0.y, acc[i][1]);
            acc[i][2] = fmaf(av, b0.z, acc[i][2]);
            acc[i][3] = fmaf(av, b0.w, acc[i][3]);
            acc[i][4] = fmaf(av, b1.x, acc[i][4]);
            acc[i][5] = fmaf(av, b1.y, acc[i][5]);
            acc[i][6] = fmaf(av, b1.z, acc[i][6]);
            acc[i][7] = fmaf(av, b1.w, acc[i][7]);
        }
    }
    #pragma unroll
    for (int i = 0; i < 2; ++i) {
        size_t ro = (size_t)(n0 + n2 + i) * 128;
        *(float4*)&Y[ro + c0]     = make_float4(acc[i][0], acc[i][1], acc[i][2], acc[i][3]);
        *(float4*)&Y[ro + c0 + 4] = make_float4(acc[i][4], acc[i][5], acc[i][6], acc[i][7]);
    }
}

// Fused node update: t = ssp(X@W1+B1); out = t@W2+B2 (+Hin); Hout = out;
// optionally XHout = out @ W3 (next layer's cl1).
template<bool RESID, bool G3>
__global__ __launch_bounds__(512, 4) void k_node2(
    const float* __restrict__ X,
    const float* __restrict__ W1, const float* __restrict__ B1,
    const float* __restrict__ W2, const float* __restrict__ B2,
    const float* __restrict__ Hin, float* __restrict__ Hout,
    const float* __restrict__ W3, float* __restrict__ XHout)
{
    __shared__ float buf[128 * 68];
    const int tid = threadIdx.x;
    const int n2 = (tid >> 4) * 2;
    const int c0 = (tid & 15) * 8;
    const int n0 = blockIdx.x * 64;
    for (int fi = tid; fi < 64 * 32; fi += 512) {
        int node = fi >> 5, kq = fi & 31;
        float4 v = *(const float4*)&X[(size_t)(n0 + node) * 128 + kq * 4];
        int nn = node ^ ((kq << 1) & 12);
        buf[(4 * kq + 0) * 68 + nn] = v.x;
        buf[(4 * kq + 1) * 68 + nn] = v.y;
        buf[(4 * kq + 2) * 68 + nn] = v.z;
        buf[(4 * kq + 3) * 68 + nn] = v.w;
    }
    __syncthreads();
    float acc[2][8];
    {
        float4 bb0 = *(const float4*)&B1[c0];
        float4 bb1 = *(const float4*)&B1[c0 + 4];
        #pragma unroll
        for (int i = 0; i < 2; ++i) {
            acc[i][0] = bb0.x; acc[i][1] = bb0.y; acc[i][2] = bb0.z; acc[i][3] = bb0.w;
            acc[i][4] = bb1.x; acc[i][5] = bb1.y; acc[i][6] = bb1.z; acc[i][7] = bb1.w;
        }
    }
    #pragma unroll 2
    for (int k = 0; k < 128; ++k) {
        float2 a = *(float2*)&buf[k * 68 + (n2 ^ SWZ(k))];
        float4 b0 = *(const float4*)&W1[k * 128 + c0];
        float4 b1 = *(const float4*)&W1[k * 128 + c0 + 4];
        #pragma unroll
        for (int i = 0; i < 2; ++i) {
            float av = ((float*)&a)[i];
            acc[i][0] = fmaf(av, b0.x, acc[i][0]);
            acc[i][1] = fmaf(av, b0.y, acc[i][1]);
            acc[i][2] = fmaf(av, b0.z, acc[i][2]);
            acc[i][3] = fmaf(av, b0.w, acc[i][3]);
            acc[i][4] = fmaf(av, b1.x, acc[i][4]);
            acc[i][5] = fmaf(av, b1.y, acc[i][5]);
            acc[i][6] = fmaf(av, b1.z, acc[i][6]);
            acc[i][7] = fmaf(av, b1.w, acc[i][7]);
        }
    }
    __syncthreads();
    #pragma unroll
    for (int j = 0; j < 8; ++j) {
        int kk = c0 + j;
        int sw = SWZ(kk);
        buf[kk * 68 + (n2 ^ sw)]       = ssp(acc[0][j]);
        buf[kk * 68 + ((n2 + 1) ^ sw)] = ssp(acc[1][j]);
    }
    __syncthreads();
    float acc2[2][8];
    {
        float4 bb0 = *(const float4*)&B2[c0];
        float4 bb1 = *(const float4*)&B2[c0 + 4];
        #pragma unroll
        for (int i = 0; i < 2; ++i) {
            acc2[i][0] = bb0.x; acc2[i][1] = bb0.y; acc2[i][2] = bb0.z; acc2[i][3] = bb0.w;
            acc2[i][4] = bb1.x; acc2[i][5] = bb1.y; acc2[i][6] = bb1.z; acc2[i][7] = bb1.w;
        }
    }
    #pragma unroll 2
    for (int k = 0; k < 128; ++k) {
        float2 a = *(float2*)&buf[k * 68 + (n2 ^ SWZ(k))];
        float4 b0 = *(const float4*)&W2[k * 128 + c0];
        float4 b1 = *(const float4*)&W2[k * 128 + c0 + 4];
        #pragma unroll
        for (int i = 0; i < 2; ++i) {
            float av = ((float*)&a)[i];
            acc2[i][0] = fmaf(av, b0.x, acc2[i][0]);
            acc2[i][1] = fmaf(av, b0.y, acc2[i][1]);
            acc2[i][2] = fmaf(av, b0.z, acc2[i][2]);
            acc2[i][3] = fmaf(av, b0.w, acc2[i][3]);
            acc2[i][4] = fmaf(av, b1.x, acc2[i][4]);
            acc2[i][5] = fmaf(av, b1.y, acc2[i][5]);
            acc2[i][6] = fmaf(av, b1.z, acc2[i][6]);
            acc2[i][7] = fmaf(av, b1.w, acc2[i][7]);
        }
    }
    #pragma unroll
    for (int i = 0; i < 2; ++i) {
        size_t ro = (size_t)(n0 + n2 + i) * 128;
        if (RESID) {
            float4 h0 = *(const float4*)&Hin[ro + c0];
            float4 h1 = *(const float4*)&Hin[ro + c0 + 4];
            acc2[i][0] += h0.x; acc2[i][1] += h0.y; acc2[i][2] += h0.z; acc2[i][3] += h0.w;
            acc2[i][4] += h1.x; acc2[i][5] += h1.y; acc2[i][6] += h1.z; acc2[i][7] += h1.w;
        }
        *(float4*)&Hout[ro + c0]     = make_float4(acc2[i][0], acc2[i][1], acc2[i][2], acc2[i][3]);
        *(float4*)&Hout[ro + c0 + 4] = make_float4(acc2[i][4], acc2[i][5], acc2[i][6], acc2[i][7]);
    }
    if (G3) {
        __syncthreads();
        #pragma unroll
        for (int j = 0; j < 8; ++j) {
            int kk = c0 + j;
            int sw = SWZ(kk);
            buf[kk * 68 + (n2 ^ sw)]       = acc2[0][j];
            buf[kk * 68 + ((n2 + 1) ^ sw)] = acc2[1][j];
        }
        __syncthreads();
        float acc3[2][8];
        #pragma unroll
        for (int i = 0; i < 2; ++i)
            #pragma unroll
            for (int j = 0; j < 8; ++j) acc3[i][j] = 0.f;
        #pragma unroll 2
        for (int k = 0; k < 128; ++k) {
            float2 a = *(float2*)&buf[k * 68 + (n2 ^ SWZ(k))];
            float4 b0 = *(const float4*)&W3[k * 128 + c0];
            float4 b1 = *(const float4*)&W3[k * 128 + c0 + 4];
            #pragma unroll
            for (int i = 0; i < 2; ++i) {
                float av = ((float*)&a)[i];
                acc3[i][0] = fmaf(av, b0.x, acc3[i][0]);
                acc3[i][1] = fmaf(av, b0.y, acc3[i][1]);
                acc3[i][2] = fmaf(av, b0.z, acc3[i][2]);
                acc3[i][3] = fmaf(av, b0.w, acc3[i][3]);
                acc3[i][4] = fmaf(av, b1.x, acc3[i][4]);
                acc3[i][5] = fmaf(av, b1.y, acc3[i][5]);
                acc3[i][6] = fmaf(av, b1.z, acc3[i][6]);
                acc3[i][7] = fmaf(av, b1.w, acc3[i][7]);
            }
        }
        #pragma unroll
        for (int i = 0; i < 2; ++i) {
            size_t ro = (size_t)(n0 + n2 + i) * 128;
            *(float4*)&XHout[ro + c0]     = make_float4(acc3[i][0], acc3[i][1], acc3[i][2], acc3[i][3]);
            *(float4*)&XHout[ro + c0 + 4] = make_float4(acc3[i][4], acc3[i][5], acc3[i][6], acc3[i][7]);
        }
    }
}

__global__ void k_pool(const float* __restrict__ hout, const int* __restrict__ batch,
                       float* __restrict__ out) {
    int g = blockIdx.x;
    int c = threadIdx.x;
    int a = 0, b = N_NODES;
    while (a < b) { int m = (a + b) >> 1; if (batch[m] < g) a = m + 1; else b = m; }
    int lo = a;
    b = N_NODES;
    while (a < b) { int m = (a + b) >> 1; if (batch[m] < g + 1) a = m + 1; else b = m; }
    int hi = a;
    float s = 0.f;
    for (int n = lo; n < hi; ++n) s += hout[n * HID + c];
    int cnt = hi - lo;
    out[g * HID + c] = s / fmaxf((float)cnt, 1.0f);
}

extern "C" void kernel_launch(void* const* d_in, const int* in_sizes, int n_in,
                              void* d_out, int out_size, void* d_ws, size_t ws_size,
                              hipStream_t stream) {
    const int*   z       = (const int*)  d_in[0];
    const float* pos     = (const float*)d_in[1];
    const int*   batch   = (const int*)  d_in[2];
    const int*   ei      = (const int*)  d_in[3];
    const float* emb     = (const float*)d_in[4];
    const float* mlp1_w  = (const float*)d_in[5];
    const float* mlp1_b  = (const float*)d_in[6];
    const float* mlp2_w  = (const float*)d_in[7];
    const float* mlp2_b  = (const float*)d_in[8];
    const float* cl1_w   = (const float*)d_in[9];
    const float* cl2_w   = (const float*)d_in[10];
    const float* cl2_b   = (const float*)d_in[11];
    const float* lin_w   = (const float*)d_in[12];
    const float* lin_b   = (const float*)d_in[13];
    const float* out1_w  = (const float*)d_in[14];
    const float* out1_b  = (const float*)d_in[15];
    const float* out2_w  = (const float*)d_in[16];
    const float* out2_b  = (const float*)d_in[17];

    float* ws     = (float*)d_ws;
    float* h      = ws;
    float* xh     = h    + (size_t)N_NODES * HID;
    float* agg    = xh   + (size_t)N_NODES * HID;
    int2*  meta   = (int2*)(agg + (size_t)N_NODES * HID);
    int*   cnt    = (int*)(meta + N_EDGES);
    int*   rowptr = cnt + N_NODES;
    int*   wo     = rowptr + N_NODES + 1;
    float* ftab   = (float*)(wo + N_NODES);   // NL*TROWS*FILT

    hipMemsetAsync(cnt, 0, N_NODES * sizeof(int), stream);
    k_embed<<<N_NODES * HID / 256, 256, 0, stream>>>(z, emb, h);
    k_hist<<<N_EDGES / 256, 256, 0, stream>>>(ei, cnt);
    k_scan<<<1, 1024, 0, stream>>>(cnt, rowptr, wo);
    k_scatter<<<N_EDGES / 256, 256, 0, stream>>>(ei, pos, wo, meta);
    k_tab<<<NL * 32, 512, 0, stream>>>(mlp1_w, mlp1_b, mlp2_w, mlp2_b, ftab);

    k_xh2<<<N_NODES / 64, 512, 0, stream>>>(h, cl1_w, xh);
    for (int i = 0; i < NL; ++i) {
        k_edge3<<<N_NODES / 4, 256, 0, stream>>>(
            meta, rowptr, xh, ftab + (size_t)i * TROWS * FILT, agg);
        if (i < NL - 1) {
            k_node2<true, true><<<N_NODES / 64, 512, 0, stream>>>(
                agg, cl2_w + (size_t)i * FILT * HID, cl2_b + (size_t)i * HID,
                lin_w + (size_t)i * HID * HID, lin_b + (size_t)i * HID,
                h, h, cl1_w + (size_t)(i + 1) * HID * FILT, xh);
        } else {
            k_node2<true, false><<<N_NODES / 64, 512, 0, stream>>>(
                agg, cl2_w + (size_t)i * FILT * HID, cl2_b + (size_t)i * HID,
                lin_w + (size_t)i * HID * HID, lin_b + (size_t)i * HID,
                h, h, nullptr, nullptr);
        }
    }
    k_node2<false, false><<<N_NODES / 64, 512, 0, stream>>>(
        h, out1_w, out1_b, out2_w, out2_b, nullptr, xh, nullptr, nullptr);
    k_pool<<<N_GRAPHS, HID, 0, stream>>>(xh, batch, (float*)d_out);
}

// Round 7
// 893.527 us; speedup vs baseline: 3.2270x; 1.1898x over previous
//
#include <hip/hip_runtime.h>
#include <math.h>

#define N_NODES 16384
#define N_EDGES 524288
#define N_GRAPHS 64
#define HID 128
#define FILT 128
#define NG 51
#define NL 6
#define TROWS 2048   // filter-table resolution
#define DMAX 8.66025404f          // 5*sqrt(3), max possible distance
#define DSTEP (DMAX / (TROWS - 1))
#define INV_DSTEP ((TROWS - 1) / DMAX)
#define EUNROLL 8

__device__ __forceinline__ float ssp(float x) {
    float sp = (x > 20.0f) ? x : log1pf(__expf(x));
    return sp - 0.6931471805599453f;
}

__global__ void k_embed(const int* __restrict__ z, const float* __restrict__ emb,
                        float* __restrict__ h) {
    int i = blockIdx.x * blockDim.x + threadIdx.x;
    int n = i >> 7, c = i & 127;
    h[i] = emb[z[n] * HID + c];
}

__global__ void k_hist(const int* __restrict__ ei, int* __restrict__ cnt) {
    int e = blockIdx.x * blockDim.x + threadIdx.x;
    if (e < N_EDGES) atomicAdd(&cnt[ei[e]], 1);
}

__global__ __launch_bounds__(1024) void k_scan(const int* __restrict__ cnt,
                                               int* __restrict__ rowptr,
                                               int* __restrict__ wo) {
    __shared__ int sums[1024];
    int t = threadIdx.x;
    int loc[16];
    int s = 0;
    #pragma unroll
    for (int i = 0; i < 16; ++i) { loc[i] = cnt[t * 16 + i]; s += loc[i]; }
    sums[t] = s;
    __syncthreads();
    for (int off = 1; off < 1024; off <<= 1) {
        int v = sums[t];
        int u = (t >= off) ? sums[t - off] : 0;
        __syncthreads();
        sums[t] = v + u;
        __syncthreads();
    }
    int ex = sums[t] - s;
    #pragma unroll
    for (int i = 0; i < 16; ++i) {
        rowptr[t * 16 + i] = ex;
        wo[t * 16 + i] = ex;
        ex += loc[i];
    }
    if (t == 1023) rowptr[16384] = ex;
}

// scatter into CSR order: meta.x = col, meta.y = ew bits
__global__ void k_scatter(const int* __restrict__ ei, const float* __restrict__ pos,
                          int* __restrict__ wo, int2* __restrict__ meta) {
    int e = blockIdx.x * blockDim.x + threadIdx.x;
    if (e >= N_EDGES) return;
    int r = ei[e], c = ei[N_EDGES + e];
    int p = atomicAdd(&wo[r], 1);
    float dx = pos[r * 3 + 0] - pos[c * 3 + 0];
    float dy = pos[r * 3 + 1] - pos[c * 3 + 1];
    float dz = pos[r * 3 + 2] - pos[c * 3 + 2];
    float ew = sqrtf(dx * dx + dy * dy + dz * dz);
    meta[p] = make_int2(c, __float_as_int(ew));
}

// Filter tables: ftab[layer][i][c] = (ssp(gauss(d_i)@W1+b1)@W2+b2)[c] * C(d_i)
__global__ __launch_bounds__(512) void k_tab(
    const float* __restrict__ mlp1_w, const float* __restrict__ mlp1_b,
    const float* __restrict__ mlp2_w, const float* __restrict__ mlp2_b,
    float* __restrict__ ftab)
{
    const int layer = blockIdx.x >> 5;
    const int tile  = blockIdx.x & 31;
    const float* W1 = mlp1_w + (size_t)layer * NG * FILT;
    const float* B1 = mlp1_b + (size_t)layer * FILT;
    const float* W2 = mlp2_w + (size_t)layer * FILT * FILT;
    const float* B2 = mlp2_b + (size_t)layer * FILT;
    float* out = ftab + (size_t)layer * TROWS * FILT + (size_t)tile * 64 * FILT;
    __shared__ float buf[FILT * 64];
    const int tid = threadIdx.x;
    const int e0 = (tid & 15) * 4;
    const int c0 = (tid >> 4) * 4;
    for (int idx = tid; idx < NG * 64; idx += 512) {
        int k = idx >> 6, e = idx & 63;
        float d = (float)(tile * 64 + e) * DSTEP;
        float dd = d - 0.2f * (float)k;
        buf[idx] = __expf(-12.5f * dd * dd);
    }
    __syncthreads();
    float acc[4][4];
    #pragma unroll
    for (int i = 0; i < 4; ++i)
        #pragma unroll
        for (int j = 0; j < 4; ++j) acc[i][j] = B1[c0 + j];
    for (int k = 0; k < NG; ++k) {
        float4 a = *(float4*)&buf[k * 64 + e0];
        float4 b = *(const float4*)&W1[k * FILT + c0];
        #pragma unroll
        for (int i = 0; i < 4; ++i)
            #pragma unroll
            for (int j = 0; j < 4; ++j)
                acc[i][j] += ((float*)&a)[i] * ((float*)&b)[j];
    }
    __syncthreads();
    #pragma unroll
    for (int j = 0; j < 4; ++j) {
        float4 w;
        ((float*)&w)[0] = ssp(acc[0][j]);
        ((float*)&w)[1] = ssp(acc[1][j]);
        ((float*)&w)[2] = ssp(acc[2][j]);
        ((float*)&w)[3] = ssp(acc[3][j]);
        *(float4*)&buf[(c0 + j) * 64 + e0] = w;
    }
    __syncthreads();
    float acc2[4][4];
    #pragma unroll
    for (int i = 0; i < 4; ++i)
        #pragma unroll
        for (int j = 0; j < 4; ++j) acc2[i][j] = B2[c0 + j];
    for (int k = 0; k < FILT; ++k) {
        float4 a = *(float4*)&buf[k * 64 + e0];
        float4 b = *(const float4*)&W2[k * FILT + c0];
        #pragma unroll
        for (int i = 0; i < 4; ++i)
            #pragma unroll
            for (int j = 0; j < 4; ++j)
                acc2[i][j] += ((float*)&a)[i] * ((float*)&b)[j];
    }
    #pragma unroll
    for (int i = 0; i < 4; ++i) {
        int r = tile * 64 + e0 + i;
        float d = (float)r * DSTEP;
        float C = 0.5f * (__cosf(d * 0.31415926535f) + 1.0f);
        #pragma unroll
        for (int j = 0; j < 4; ++j)
            out[(e0 + i) * FILT + c0 + j] = acc2[i][j] * C;
    }
}

// Wave-per-row edge aggregation: each wave owns one destination row, lane
// holds 2 channels of the accumulator in registers. No LDS, no atomics.
__global__ __launch_bounds__(256) void k_edge3(
    const int2* __restrict__ meta, const int* __restrict__ rowptr,
    const float* __restrict__ xh, const float* __restrict__ tab,
    float* __restrict__ agg)
{
    const int row = blockIdx.x * 4 + (threadIdx.x >> 6);
    const int c2 = (threadIdx.x & 63) * 2;
    const int es = rowptr[row], ee = rowptr[row + 1];
    float ax = 0.f, ay = 0.f;
    for (int e = es; e < ee; e += EUNROLL) {
        float2 t0[EUNROLL], t1[EUNROLL], xv[EUNROLL];
        float f[EUNROLL], sc[EUNROLL];
        #pragma unroll
        for (int u = 0; u < EUNROLL; ++u) {
            int ec = min(e + u, ee - 1);
            sc[u] = (e + u < ee) ? 1.f : 0.f;
            int2 m = meta[ec];                       // wave-uniform broadcast
            float d = __int_as_float(m.y);
            float uu = d * INV_DSTEP;
            int i0 = min((int)uu, TROWS - 2);
            f[u] = uu - (float)i0;
            t0[u] = *(const float2*)&tab[(size_t)i0 * FILT + c2];
            t1[u] = *(const float2*)&tab[(size_t)(i0 + 1) * FILT + c2];
            xv[u] = *(const float2*)&xh[(size_t)m.x * FILT + c2];
        }
        #pragma unroll
        for (int u = 0; u < EUNROLL; ++u) {
            float wx = fmaf(f[u], t1[u].x - t0[u].x, t0[u].x) * sc[u];
            float wy = fmaf(f[u], t1[u].y - t0[u].y, t0[u].y) * sc[u];
            ax = fmaf(wx, xv[u].x, ax);
            ay = fmaf(wy, xv[u].y, ay);
        }
    }
    *(float2*)&agg[(size_t)row * FILT + c2] = make_float2(ax, ay);
}

// ---------------------------------------------------------------------------
// Wave-per-channel-group node GEMMs.
// Block = 1024 threads = 16 waves; wave w owns output channels [8w, 8w+8);
// node = lane (64-node tile). Grid = 256. X staged transposed in LDS so the
// A-operand is a conflict-free ds_read_b32; weight-row addresses are
// wave-uniform (readfirstlane) -> scalar s_load path, no vector-L1 pressure.
// ---------------------------------------------------------------------------

// Stage X^T into buf[k][node] (node = fi&63 -> conflict-free LDS writes)
__device__ __forceinline__ void stage_xt(const float* __restrict__ X, int n0,
                                         float* __restrict__ buf, int tid) {
    #pragma unroll
    for (int it = 0; it < 2; ++it) {
        int fi = tid + it * 1024;
        int node = fi & 63, kq = fi >> 6;   // kq 0..31
        float4 v = *(const float4*)&X[(size_t)(n0 + node) * 128 + kq * 4];
        buf[(4 * kq + 0) * 68 + node] = v.x;
        buf[(4 * kq + 1) * 68 + node] = v.y;
        buf[(4 * kq + 2) * 68 + node] = v.z;
        buf[(4 * kq + 3) * 68 + node] = v.w;
    }
}

// Single GEMM: Y = X @ W (no bias) — for the initial xh = h @ cl1_w[0]
__global__ __launch_bounds__(1024, 4) void k_gemm0(const float* __restrict__ X,
                                                   const float* __restrict__ W,
                                                   float* __restrict__ Y) {
    __shared__ float bufA[128 * 68];
    const int tid = threadIdx.x;
    const int lane = tid & 63;
    const int ch0 = __builtin_amdgcn_readfirstlane(tid >> 6) * 8;
    const int n0 = blockIdx.x * 64;
    stage_xt(X, n0, bufA, tid);
    __syncthreads();
    float acc[8];
    #pragma unroll
    for (int j = 0; j < 8; ++j) acc[j] = 0.f;
    #pragma unroll 4
    for (int k = 0; k < 128; ++k) {
        float a = bufA[k * 68 + lane];
        float4 w0 = *(const float4*)&W[k * 128 + ch0];
        float4 w1 = *(const float4*)&W[k * 128 + ch0 + 4];
        acc[0] = fmaf(a, w0.x, acc[0]); acc[1] = fmaf(a, w0.y, acc[1]);
        acc[2] = fmaf(a, w0.z, acc[2]); acc[3] = fmaf(a, w0.w, acc[3]);
        acc[4] = fmaf(a, w1.x, acc[4]); acc[5] = fmaf(a, w1.y, acc[5]);
        acc[6] = fmaf(a, w1.z, acc[6]); acc[7] = fmaf(a, w1.w, acc[7]);
    }
    size_t ro = (size_t)(n0 + lane) * 128 + ch0;
    *(float4*)&Y[ro]     = make_float4(acc[0], acc[1], acc[2], acc[3]);
    *(float4*)&Y[ro + 4] = make_float4(acc[4], acc[5], acc[6], acc[7]);
}

// Fused node chain: t = ssp(X@W1+B1); out = t@W2+B2 (+Hin); Hout = out;
// optionally XHout = out @ W3 (next layer's cl1).
template<bool RESID, bool G3>
__global__ __launch_bounds__(1024, 4) void k_node3(
    const float* __restrict__ X,
    const float* __restrict__ W1, const float* __restrict__ B1,
    const float* __restrict__ W2, const float* __restrict__ B2,
    const float* __restrict__ Hin, float* __restrict__ Hout,
    const float* __restrict__ W3, float* __restrict__ XHout)
{
    __shared__ float bufA[128 * 68];
    __shared__ float bufB[128 * 68];
    const int tid = threadIdx.x;
    const int lane = tid & 63;
    const int ch0 = __builtin_amdgcn_readfirstlane(tid >> 6) * 8;
    const int n0 = blockIdx.x * 64;
    stage_xt(X, n0, bufA, tid);
    __syncthreads();
    // GEMM1 (+bias, ssp) -> bufB[ch][node]
    float acc[8];
    #pragma unroll
    for (int j = 0; j < 8; ++j) acc[j] = B1[ch0 + j];
    #pragma unroll 4
    for (int k = 0; k < 128; ++k) {
        float a = bufA[k * 68 + lane];
        float4 w0 = *(const float4*)&W1[k * 128 + ch0];
        float4 w1 = *(const float4*)&W1[k * 128 + ch0 + 4];
        acc[0] = fmaf(a, w0.x, acc[0]); acc[1] = fmaf(a, w0.y, acc[1]);
        acc[2] = fmaf(a, w0.z, acc[2]); acc[3] = fmaf(a, w0.w, acc[3]);
        acc[4] = fmaf(a, w1.x, acc[4]); acc[5] = fmaf(a, w1.y, acc[5]);
        acc[6] = fmaf(a, w1.z, acc[6]); acc[7] = fmaf(a, w1.w, acc[7]);
    }
    #pragma unroll
    for (int j = 0; j < 8; ++j)
        bufB[(ch0 + j) * 68 + lane] = ssp(acc[j]);
    __syncthreads();
    // GEMM2 (+bias, +residual) -> Hout, and transposed into bufA for GEMM3
    float acc2[8];
    #pragma unroll
    for (int j = 0; j < 8; ++j) acc2[j] = B2[ch0 + j];
    #pragma unroll 4
    for (int k = 0; k < 128; ++k) {
        float a = bufB[k * 68 + lane];
        float4 w0 = *(const float4*)&W2[k * 128 + ch0];
        float4 w1 = *(const float4*)&W2[k * 128 + ch0 + 4];
        acc2[0] = fmaf(a, w0.x, acc2[0]); acc2[1] = fmaf(a, w0.y, acc2[1]);
        acc2[2] = fmaf(a, w0.z, acc2[2]); acc2[3] = fmaf(a, w0.w, acc2[3]);
        acc2[4] = fmaf(a, w1.x, acc2[4]); acc2[5] = fmaf(a, w1.y, acc2[5]);
        acc2[6] = fmaf(a, w1.z, acc2[6]); acc2[7] = fmaf(a, w1.w, acc2[7]);
    }
    size_t ro = (size_t)(n0 + lane) * 128 + ch0;
    if (RESID) {
        float4 h0 = *(const float4*)&Hin[ro];
        float4 h1 = *(const float4*)&Hin[ro + 4];
        acc2[0] += h0.x; acc2[1] += h0.y; acc2[2] += h0.z; acc2[3] += h0.w;
        acc2[4] += h1.x; acc2[5] += h1.y; acc2[6] += h1.z; acc2[7] += h1.w;
    }
    *(float4*)&Hout[ro]     = make_float4(acc2[0], acc2[1], acc2[2], acc2[3]);
    *(float4*)&Hout[ro + 4] = make_float4(acc2[4], acc2[5], acc2[6], acc2[7]);
    if (G3) {
        // all waves finished reading bufA in GEMM1 (barrier above); GEMM2 reads
        // only bufB, so bufA is free to take out^T. Barrier before reads.
        #pragma unroll
        for (int j = 0; j < 8; ++j)
            bufA[(ch0 + j) * 68 + lane] = acc2[j];
        __syncthreads();
        float acc3[8];
        #pragma unroll
        for (int j = 0; j < 8; ++j) acc3[j] = 0.f;
        #pragma unroll 4
        for (int k = 0; k < 128; ++k) {
            float a = bufA[k * 68 + lane];
            float4 w0 = *(const float4*)&W3[k * 128 + ch0];
            float4 w1 = *(const float4*)&W3[k * 128 + ch0 + 4];
            acc3[0] = fmaf(a, w0.x, acc3[0]); acc3[1] = fmaf(a, w0.y, acc3[1]);
            acc3[2] = fmaf(a, w0.z, acc3[2]); acc3[3] = fmaf(a, w0.w, acc3[3]);
            acc3[4] = fmaf(a, w1.x, acc3[4]); acc3[5] = fmaf(a, w1.y, acc3[5]);
            acc3[6] = fmaf(a, w1.z, acc3[6]); acc3[7] = fmaf(a, w1.w, acc3[7]);
        }
        *(float4*)&XHout[ro]     = make_float4(acc3[0], acc3[1], acc3[2], acc3[3]);
        *(float4*)&XHout[ro + 4] = make_float4(acc3[4], acc3[5], acc3[6], acc3[7]);
    }
}

__global__ void k_pool(const float* __restrict__ hout, const int* __restrict__ batch,
                       float* __restrict__ out) {
    int g = blockIdx.x;
    int c = threadIdx.x;
    int a = 0, b = N_NODES;
    while (a < b) { int m = (a + b) >> 1; if (batch[m] < g) a = m + 1; else b = m; }
    int lo = a;
    b = N_NODES;
    while (a < b) { int m = (a + b) >> 1; if (batch[m] < g + 1) a = m + 1; else b = m; }
    int hi = a;
    float s = 0.f;
    for (int n = lo; n < hi; ++n) s += hout[n * HID + c];
    int cnt = hi - lo;
    out[g * HID + c] = s / fmaxf((float)cnt, 1.0f);
}

extern "C" void kernel_launch(void* const* d_in, const int* in_sizes, int n_in,
                              void* d_out, int out_size, void* d_ws, size_t ws_size,
                              hipStream_t stream) {
    const int*   z       = (const int*)  d_in[0];
    const float* pos     = (const float*)d_in[1];
    const int*   batch   = (const int*)  d_in[2];
    const int*   ei      = (const int*)  d_in[3];
    const float* emb     = (const float*)d_in[4];
    const float* mlp1_w  = (const float*)d_in[5];
    const float* mlp1_b  = (const float*)d_in[6];
    const float* mlp2_w  = (const float*)d_in[7];
    const float* mlp2_b  = (const float*)d_in[8];
    const float* cl1_w   = (const float*)d_in[9];
    const float* cl2_w   = (const float*)d_in[10];
    const float* cl2_b   = (const float*)d_in[11];
    const float* lin_w   = (const float*)d_in[12];
    const float* lin_b   = (const float*)d_in[13];
    const float* out1_w  = (const float*)d_in[14];
    const float* out1_b  = (const float*)d_in[15];
    const float* out2_w  = (const float*)d_in[16];
    const float* out2_b  = (const float*)d_in[17];

    float* ws     = (float*)d_ws;
    float* h      = ws;
    float* xh     = h    + (size_t)N_NODES * HID;
    float* agg    = xh   + (size_t)N_NODES * HID;
    int2*  meta   = (int2*)(agg + (size_t)N_NODES * HID);
    int*   cnt    = (int*)(meta + N_EDGES);
    int*   rowptr = cnt + N_NODES;
    int*   wo     = rowptr + N_NODES + 1;
    float* ftab   = (float*)(wo + N_NODES);   // NL*TROWS*FILT

    hipMemsetAsync(cnt, 0, N_NODES * sizeof(int), stream);
    k_embed<<<N_NODES * HID / 256, 256, 0, stream>>>(z, emb, h);
    k_hist<<<N_EDGES / 256, 256, 0, stream>>>(ei, cnt);
    k_scan<<<1, 1024, 0, stream>>>(cnt, rowptr, wo);
    k_scatter<<<N_EDGES / 256, 256, 0, stream>>>(ei, pos, wo, meta);
    k_tab<<<NL * 32, 512, 0, stream>>>(mlp1_w, mlp1_b, mlp2_w, mlp2_b, ftab);

    k_gemm0<<<N_NODES / 64, 1024, 0, stream>>>(h, cl1_w, xh);
    for (int i = 0; i < NL; ++i) {
        k_edge3<<<N_NODES / 4, 256, 0, stream>>>(
            meta, rowptr, xh, ftab + (size_t)i * TROWS * FILT, agg);
        if (i < NL - 1) {
            k_node3<true, true><<<N_NODES / 64, 1024, 0, stream>>>(
                agg, cl2_w + (size_t)i * FILT * HID, cl2_b + (size_t)i * HID,
                lin_w + (size_t)i * HID * HID, lin_b + (size_t)i * HID,
                h, h, cl1_w + (size_t)(i + 1) * HID * FILT, xh);
        } else {
            k_node3<true, false><<<N_NODES / 64, 1024, 0, stream>>>(
                agg, cl2_w + (size_t)i * FILT * HID, cl2_b + (size_t)i * HID,
                lin_w + (size_t)i * HID * HID, lin_b + (size_t)i * HID,
                h, h, nullptr, nullptr);
        }
    }
    k_node3<false, false><<<N_NODES / 64, 1024, 0, stream>>>(
        h, out1_w, out1_b, out2_w, out2_b, nullptr, xh, nullptr, nullptr);
    k_pool<<<N_GRAPHS, HID, 0, stream>>>(xh, batch, (float*)d_out);
}

// Round 8
// 851.599 us; speedup vs baseline: 3.3858x; 1.0492x over previous
//
#include <hip/hip_runtime.h>
#include <math.h>

#define N_NODES 16384
#define N_EDGES 524288
#define N_GRAPHS 64
#define HID 128
#define FILT 128
#define NG 51
#define NL 6
#define TROWS 2048   // filter-table resolution
#define DMAX 8.66025404f          // 5*sqrt(3), max possible distance
#define DSTEP (DMAX / (TROWS - 1))
#define INV_DSTEP ((TROWS - 1) / DMAX)
#define EUNROLL 8

__device__ __forceinline__ float ssp(float x) {
    float sp = (x > 20.0f) ? x : log1pf(__expf(x));
    return sp - 0.6931471805599453f;
}

__global__ void k_embed(const int* __restrict__ z, const float* __restrict__ emb,
                        float* __restrict__ h) {
    int i = blockIdx.x * blockDim.x + threadIdx.x;
    int n = i >> 7, c = i & 127;
    h[i] = emb[z[n] * HID + c];
}

__global__ void k_hist(const int* __restrict__ ei, int* __restrict__ cnt) {
    int e = blockIdx.x * blockDim.x + threadIdx.x;
    if (e < N_EDGES) atomicAdd(&cnt[ei[e]], 1);
}

__global__ __launch_bounds__(1024) void k_scan(const int* __restrict__ cnt,
                                               int* __restrict__ rowptr,
                                               int* __restrict__ wo) {
    __shared__ int sums[1024];
    int t = threadIdx.x;
    int loc[16];
    int s = 0;
    #pragma unroll
    for (int i = 0; i < 16; ++i) { loc[i] = cnt[t * 16 + i]; s += loc[i]; }
    sums[t] = s;
    __syncthreads();
    for (int off = 1; off < 1024; off <<= 1) {
        int v = sums[t];
        int u = (t >= off) ? sums[t - off] : 0;
        __syncthreads();
        sums[t] = v + u;
        __syncthreads();
    }
    int ex = sums[t] - s;
    #pragma unroll
    for (int i = 0; i < 16; ++i) {
        rowptr[t * 16 + i] = ex;
        wo[t * 16 + i] = ex;
        ex += loc[i];
    }
    if (t == 1023) rowptr[16384] = ex;
}

// scatter into CSR order: meta.x = col, meta.y = ew bits
__global__ void k_scatter(const int* __restrict__ ei, const float* __restrict__ pos,
                          int* __restrict__ wo, int2* __restrict__ meta) {
    int e = blockIdx.x * blockDim.x + threadIdx.x;
    if (e >= N_EDGES) return;
    int r = ei[e], c = ei[N_EDGES + e];
    int p = atomicAdd(&wo[r], 1);
    float dx = pos[r * 3 + 0] - pos[c * 3 + 0];
    float dy = pos[r * 3 + 1] - pos[c * 3 + 1];
    float dz = pos[r * 3 + 2] - pos[c * 3 + 2];
    float ew = sqrtf(dx * dx + dy * dy + dz * dz);
    meta[p] = make_int2(c, __float_as_int(ew));
}

// Filter tables in INTERLEAVED layout:
// entry e = i*64 + cp (cp = channel-pair index, 0..63) is a float4
//   { W[i][2cp], W[i][2cp+1], W[i+1][2cp], W[i+1][2cp+1] }   (W includes *C(d))
// so one dwordx4 per lane yields both lerp endpoints for its 2 channels.
__global__ __launch_bounds__(512) void k_tab(
    const float* __restrict__ mlp1_w, const float* __restrict__ mlp1_b,
    const float* __restrict__ mlp2_w, const float* __restrict__ mlp2_b,
    float* __restrict__ ftab)
{
    const int layer = blockIdx.x >> 5;
    const int tile  = blockIdx.x & 31;
    const float* W1 = mlp1_w + (size_t)layer * NG * FILT;
    const float* B1 = mlp1_b + (size_t)layer * FILT;
    const float* W2 = mlp2_w + (size_t)layer * FILT * FILT;
    const float* B2 = mlp2_b + (size_t)layer * FILT;
    float* Tf = ftab + (size_t)layer * TROWS * 64 * 4;
    __shared__ float buf[FILT * 64];
    const int tid = threadIdx.x;
    const int e0 = (tid & 15) * 4;
    const int c0 = (tid >> 4) * 4;
    for (int idx = tid; idx < NG * 64; idx += 512) {
        int k = idx >> 6, e = idx & 63;
        float d = (float)(tile * 64 + e) * DSTEP;
        float dd = d - 0.2f * (float)k;
        buf[idx] = __expf(-12.5f * dd * dd);
    }
    __syncthreads();
    float acc[4][4];
    #pragma unroll
    for (int i = 0; i < 4; ++i)
        #pragma unroll
        for (int j = 0; j < 4; ++j) acc[i][j] = B1[c0 + j];
    for (int k = 0; k < NG; ++k) {
        float4 a = *(float4*)&buf[k * 64 + e0];
        float4 b = *(const float4*)&W1[k * FILT + c0];
        #pragma unroll
        for (int i = 0; i < 4; ++i)
            #pragma unroll
            for (int j = 0; j < 4; ++j)
                acc[i][j] += ((float*)&a)[i] * ((float*)&b)[j];
    }
    __syncthreads();
    #pragma unroll
    for (int j = 0; j < 4; ++j) {
        float4 w;
        ((float*)&w)[0] = ssp(acc[0][j]);
        ((float*)&w)[1] = ssp(acc[1][j]);
        ((float*)&w)[2] = ssp(acc[2][j]);
        ((float*)&w)[3] = ssp(acc[3][j]);
        *(float4*)&buf[(c0 + j) * 64 + e0] = w;
    }
    __syncthreads();
    float acc2[4][4];
    #pragma unroll
    for (int i = 0; i < 4; ++i)
        #pragma unroll
        for (int j = 0; j < 4; ++j) acc2[i][j] = B2[c0 + j];
    for (int k = 0; k < FILT; ++k) {
        float4 a = *(float4*)&buf[k * 64 + e0];
        float4 b = *(const float4*)&W2[k * FILT + c0];
        #pragma unroll
        for (int i = 0; i < 4; ++i)
            #pragma unroll
            for (int j = 0; j < 4; ++j)
                acc2[i][j] += ((float*)&a)[i] * ((float*)&b)[j];
    }
    #pragma unroll
    for (int i = 0; i < 4; ++i) {
        int r = tile * 64 + e0 + i;
        float d = (float)r * DSTEP;
        float C = 0.5f * (__cosf(d * 0.31415926535f) + 1.0f);
        float v0 = acc2[i][0] * C, v1 = acc2[i][1] * C;
        float v2 = acc2[i][2] * C, v3 = acc2[i][3] * C;
        int cp = c0 >> 1;   // channel-pair index of c0
        if (r <= TROWS - 2) {       // row r is the "t0" of entry r
            *(float2*)&Tf[((size_t)r * 64 + cp) * 4]       = make_float2(v0, v1);
            *(float2*)&Tf[((size_t)r * 64 + cp + 1) * 4]   = make_float2(v2, v3);
        }
        if (r >= 1) {               // row r is the "t1" of entry r-1
            *(float2*)&Tf[((size_t)(r - 1) * 64 + cp) * 4 + 2]     = make_float2(v0, v1);
            *(float2*)&Tf[((size_t)(r - 1) * 64 + cp + 1) * 4 + 2] = make_float2(v2, v3);
        }
    }
}

// Wave-per-row edge aggregation; interleaved table (1 dwordx4 + 1 dwordx2 per
// edge per lane). 8 waves/block, 32 waves/CU. No LDS, no atomics.
__global__ __launch_bounds__(512, 8) void k_edge4(
    const int2* __restrict__ meta, const int* __restrict__ rowptr,
    const float* __restrict__ xh, const float* __restrict__ Tf,
    float* __restrict__ agg)
{
    const int row = blockIdx.x * 8 + (threadIdx.x >> 6);
    const int lane = threadIdx.x & 63;
    const int c2 = lane * 2;
    const int es = rowptr[row], ee = rowptr[row + 1];
    float ax = 0.f, ay = 0.f;
    if (es < ee) {
        for (int e = es; e < ee; e += EUNROLL) {
            float4 tt[EUNROLL];
            float2 xv[EUNROLL];
            float f[EUNROLL], sc[EUNROLL];
            #pragma unroll
            for (int u = 0; u < EUNROLL; ++u) {
                int ec = min(e + u, ee - 1);
                sc[u] = (e + u < ee) ? 1.f : 0.f;
                int2 m = meta[ec];
                float d = __int_as_float(m.y);
                float uu = d * INV_DSTEP;
                int i0 = min((int)uu, TROWS - 2);
                f[u] = uu - (float)i0;
                tt[u] = *(const float4*)&Tf[((size_t)i0 * 64 + lane) * 4];
                xv[u] = *(const float2*)&xh[(size_t)m.x * FILT + c2];
            }
            #pragma unroll
            for (int u = 0; u < EUNROLL; ++u) {
                float wx = fmaf(f[u], tt[u].z - tt[u].x, tt[u].x) * sc[u];
                float wy = fmaf(f[u], tt[u].w - tt[u].y, tt[u].y) * sc[u];
                ax = fmaf(wx, xv[u].x, ax);
                ay = fmaf(wy, xv[u].y, ay);
            }
        }
    }
    *(float2*)&agg[(size_t)row * FILT + c2] = make_float2(ax, ay);
}

// ---------------------------------------------------------------------------
// Wave-per-channel-group node GEMMs (unchanged from R7).
// ---------------------------------------------------------------------------
__device__ __forceinline__ void stage_xt(const float* __restrict__ X, int n0,
                                         float* __restrict__ buf, int tid) {
    #pragma unroll
    for (int it = 0; it < 2; ++it) {
        int fi = tid + it * 1024;
        int node = fi & 63, kq = fi >> 6;
        float4 v = *(const float4*)&X[(size_t)(n0 + node) * 128 + kq * 4];
        buf[(4 * kq + 0) * 68 + node] = v.x;
        buf[(4 * kq + 1) * 68 + node] = v.y;
        buf[(4 * kq + 2) * 68 + node] = v.z;
        buf[(4 * kq + 3) * 68 + node] = v.w;
    }
}

__global__ __launch_bounds__(1024, 4) void k_gemm0(const float* __restrict__ X,
                                                   const float* __restrict__ W,
                                                   float* __restrict__ Y) {
    __shared__ float bufA[128 * 68];
    const int tid = threadIdx.x;
    const int lane = tid & 63;
    const int ch0 = __builtin_amdgcn_readfirstlane(tid >> 6) * 8;
    const int n0 = blockIdx.x * 64;
    stage_xt(X, n0, bufA, tid);
    __syncthreads();
    float acc[8];
    #pragma unroll
    for (int j = 0; j < 8; ++j) acc[j] = 0.f;
    #pragma unroll 4
    for (int k = 0; k < 128; ++k) {
        float a = bufA[k * 68 + lane];
        float4 w0 = *(const float4*)&W[k * 128 + ch0];
        float4 w1 = *(const float4*)&W[k * 128 + ch0 + 4];
        acc[0] = fmaf(a, w0.x, acc[0]); acc[1] = fmaf(a, w0.y, acc[1]);
        acc[2] = fmaf(a, w0.z, acc[2]); acc[3] = fmaf(a, w0.w, acc[3]);
        acc[4] = fmaf(a, w1.x, acc[4]); acc[5] = fmaf(a, w1.y, acc[5]);
        acc[6] = fmaf(a, w1.z, acc[6]); acc[7] = fmaf(a, w1.w, acc[7]);
    }
    size_t ro = (size_t)(n0 + lane) * 128 + ch0;
    *(float4*)&Y[ro]     = make_float4(acc[0], acc[1], acc[2], acc[3]);
    *(float4*)&Y[ro + 4] = make_float4(acc[4], acc[5], acc[6], acc[7]);
}

template<bool RESID, bool G3>
__global__ __launch_bounds__(1024, 4) void k_node3(
    const float* __restrict__ X,
    const float* __restrict__ W1, const float* __restrict__ B1,
    const float* __restrict__ W2, const float* __restrict__ B2,
    const float* __restrict__ Hin, float* __restrict__ Hout,
    const float* __restrict__ W3, float* __restrict__ XHout)
{
    __shared__ float bufA[128 * 68];
    __shared__ float bufB[128 * 68];
    const int tid = threadIdx.x;
    const int lane = tid & 63;
    const int ch0 = __builtin_amdgcn_readfirstlane(tid >> 6) * 8;
    const int n0 = blockIdx.x * 64;
    stage_xt(X, n0, bufA, tid);
    __syncthreads();
    float acc[8];
    #pragma unroll
    for (int j = 0; j < 8; ++j) acc[j] = B1[ch0 + j];
    #pragma unroll 4
    for (int k = 0; k < 128; ++k) {
        float a = bufA[k * 68 + lane];
        float4 w0 = *(const float4*)&W1[k * 128 + ch0];
        float4 w1 = *(const float4*)&W1[k * 128 + ch0 + 4];
        acc[0] = fmaf(a, w0.x, acc[0]); acc[1] = fmaf(a, w0.y, acc[1]);
        acc[2] = fmaf(a, w0.z, acc[2]); acc[3] = fmaf(a, w0.w, acc[3]);
        acc[4] = fmaf(a, w1.x, acc[4]); acc[5] = fmaf(a, w1.y, acc[5]);
        acc[6] = fmaf(a, w1.z, acc[6]); acc[7] = fmaf(a, w1.w, acc[7]);
    }
    #pragma unroll
    for (int j = 0; j < 8; ++j)
        bufB[(ch0 + j) * 68 + lane] = ssp(acc[j]);
    __syncthreads();
    float acc2[8];
    #pragma unroll
    for (int j = 0; j < 8; ++j) acc2[j] = B2[ch0 + j];
    #pragma unroll 4
    for (int k = 0; k < 128; ++k) {
        float a = bufB[k * 68 + lane];
        float4 w0 = *(const float4*)&W2[k * 128 + ch0];
        float4 w1 = *(const float4*)&W2[k * 128 + ch0 + 4];
        acc2[0] = fmaf(a, w0.x, acc2[0]); acc2[1] = fmaf(a, w0.y, acc2[1]);
        acc2[2] = fmaf(a, w0.z, acc2[2]); acc2[3] = fmaf(a, w0.w, acc2[3]);
        acc2[4] = fmaf(a, w1.x, acc2[4]); acc2[5] = fmaf(a, w1.y, acc2[5]);
        acc2[6] = fmaf(a, w1.z, acc2[6]); acc2[7] = fmaf(a, w1.w, acc2[7]);
    }
    size_t ro = (size_t)(n0 + lane) * 128 + ch0;
    if (RESID) {
        float4 h0 = *(const float4*)&Hin[ro];
        float4 h1 = *(const float4*)&Hin[ro + 4];
        acc2[0] += h0.x; acc2[1] += h0.y; acc2[2] += h0.z; acc2[3] += h0.w;
        acc2[4] += h1.x; acc2[5] += h1.y; acc2[6] += h1.z; acc2[7] += h1.w;
    }
    *(float4*)&Hout[ro]     = make_float4(acc2[0], acc2[1], acc2[2], acc2[3]);
    *(float4*)&Hout[ro + 4] = make_float4(acc2[4], acc2[5], acc2[6], acc2[7]);
    if (G3) {
        #pragma unroll
        for (int j = 0; j < 8; ++j)
            bufA[(ch0 + j) * 68 + lane] = acc2[j];
        __syncthreads();
        float acc3[8];
        #pragma unroll
        for (int j = 0; j < 8; ++j) acc3[j] = 0.f;
        #pragma unroll 4
        for (int k = 0; k < 128; ++k) {
            float a = bufA[k * 68 + lane];
            float4 w0 = *(const float4*)&W3[k * 128 + ch0];
            float4 w1 = *(const float4*)&W3[k * 128 + ch0 + 4];
            acc3[0] = fmaf(a, w0.x, acc3[0]); acc3[1] = fmaf(a, w0.y, acc3[1]);
            acc3[2] = fmaf(a, w0.z, acc3[2]); acc3[3] = fmaf(a, w0.w, acc3[3]);
            acc3[4] = fmaf(a, w1.x, acc3[4]); acc3[5] = fmaf(a, w1.y, acc3[5]);
            acc3[6] = fmaf(a, w1.z, acc3[6]); acc3[7] = fmaf(a, w1.w, acc3[7]);
        }
        *(float4*)&XHout[ro]     = make_float4(acc3[0], acc3[1], acc3[2], acc3[3]);
        *(float4*)&XHout[ro + 4] = make_float4(acc3[4], acc3[5], acc3[6], acc3[7]);
    }
}

// Partial-sum pooling: block b sums nodes [64b, 64b+64) per channel, using
// sortedness of batch; ~1-3 atomics per (block, channel).
__global__ __launch_bounds__(128) void k_pool2(const float* __restrict__ x,
                                               const int* __restrict__ batch,
                                               float* __restrict__ gsum) {
    const int c = threadIdx.x;
    const int n0 = blockIdx.x * 64;
    float acc = 0.f;
    int cur = batch[n0];
    for (int i = 0; i < 64; ++i) {
        int g = batch[n0 + i];
        float v = x[(size_t)(n0 + i) * 128 + c];
        if (g != cur) {
            atomicAdd(&gsum[cur * 128 + c], acc);
            acc = 0.f;
            cur = g;
        }
        acc += v;
    }
    atomicAdd(&gsum[cur * 128 + c], acc);
}

__global__ void k_div(const float* __restrict__ gsum, const int* __restrict__ batch,
                      float* __restrict__ out) {
    int g = blockIdx.x;
    int c = threadIdx.x;
    int a = 0, b = N_NODES;
    while (a < b) { int m = (a + b) >> 1; if (batch[m] < g) a = m + 1; else b = m; }
    int lo = a;
    b = N_NODES;
    while (a < b) { int m = (a + b) >> 1; if (batch[m] < g + 1) a = m + 1; else b = m; }
    int cnt = a - lo;
    out[g * 128 + c] = gsum[g * 128 + c] / fmaxf((float)cnt, 1.0f);
}

extern "C" void kernel_launch(void* const* d_in, const int* in_sizes, int n_in,
                              void* d_out, int out_size, void* d_ws, size_t ws_size,
                              hipStream_t stream) {
    const int*   z       = (const int*)  d_in[0];
    const float* pos     = (const float*)d_in[1];
    const int*   batch   = (const int*)  d_in[2];
    const int*   ei      = (const int*)  d_in[3];
    const float* emb     = (const float*)d_in[4];
    const float* mlp1_w  = (const float*)d_in[5];
    const float* mlp1_b  = (const float*)d_in[6];
    const float* mlp2_w  = (const float*)d_in[7];
    const float* mlp2_b  = (const float*)d_in[8];
    const float* cl1_w   = (const float*)d_in[9];
    const float* cl2_w   = (const float*)d_in[10];
    const float* cl2_b   = (const float*)d_in[11];
    const float* lin_w   = (const float*)d_in[12];
    const float* lin_b   = (const float*)d_in[13];
    const float* out1_w  = (const float*)d_in[14];
    const float* out1_b  = (const float*)d_in[15];
    const float* out2_w  = (const float*)d_in[16];
    const float* out2_b  = (const float*)d_in[17];

    float* ws     = (float*)d_ws;
    float* h      = ws;
    float* xh     = h    + (size_t)N_NODES * HID;
    float* agg    = xh   + (size_t)N_NODES * HID;
    int2*  meta   = (int2*)(agg + (size_t)N_NODES * HID);
    int*   cnt    = (int*)(meta + N_EDGES);
    int*   rowptr = cnt + N_NODES;
    int*   wo     = rowptr + N_NODES + 1;
    float* gsum   = (float*)(wo + N_NODES);            // 64*128
    float* ftab   = gsum + N_GRAPHS * 128;             // NL*TROWS*64*4 floats

    hipMemsetAsync(cnt, 0, N_NODES * sizeof(int), stream);
    hipMemsetAsync(gsum, 0, N_GRAPHS * 128 * sizeof(float), stream);
    k_embed<<<N_NODES * HID / 256, 256, 0, stream>>>(z, emb, h);
    k_hist<<<N_EDGES / 256, 256, 0, stream>>>(ei, cnt);
    k_scan<<<1, 1024, 0, stream>>>(cnt, rowptr, wo);
    k_scatter<<<N_EDGES / 256, 256, 0, stream>>>(ei, pos, wo, meta);
    k_tab<<<NL * 32, 512, 0, stream>>>(mlp1_w, mlp1_b, mlp2_w, mlp2_b, ftab);

    k_gemm0<<<N_NODES / 64, 1024, 0, stream>>>(h, cl1_w, xh);
    for (int i = 0; i < NL; ++i) {
        k_edge4<<<N_NODES / 8, 512, 0, stream>>>(
            meta, rowptr, xh, ftab + (size_t)i * TROWS * 64 * 4, agg);
        if (i < NL - 1) {
            k_node3<true, true><<<N_NODES / 64, 1024, 0, stream>>>(
                agg, cl2_w + (size_t)i * FILT * HID, cl2_b + (size_t)i * HID,
                lin_w + (size_t)i * HID * HID, lin_b + (size_t)i * HID,
                h, h, cl1_w + (size_t)(i + 1) * HID * FILT, xh);
        } else {
            k_node3<true, false><<<N_NODES / 64, 1024, 0, stream>>>(
                agg, cl2_w + (size_t)i * FILT * HID, cl2_b + (size_t)i * HID,
                lin_w + (size_t)i * HID * HID, lin_b + (size_t)i * HID,
                h, h, nullptr, nullptr);
        }
    }
    k_node3<false, false><<<N_NODES / 64, 1024, 0, stream>>>(
        h, out1_w, out1_b, out2_w, out2_b, nullptr, xh, nullptr, nullptr);
    k_pool2<<<N_NODES / 64, 128, 0, stream>>>(xh, batch, gsum);
    k_div<<<N_GRAPHS, 128, 0, stream>>>(gsum, batch, (float*)d_out);
}

// Round 9
// 822.927 us; speedup vs baseline: 3.5038x; 1.0348x over previous
//
#include <hip/hip_runtime.h>
#include <math.h>

#define N_NODES 16384
#define N_EDGES 524288
#define N_GRAPHS 64
#define HID 128
#define FILT 128
#define NG 51
#define NL 6
#define TROWS 2048   // filter-table resolution
#define DMAX 8.66025404f          // 5*sqrt(3), max possible distance
#define DSTEP (DMAX / (TROWS - 1))
#define INV_DSTEP ((TROWS - 1) / DMAX)
#define EUNROLL 4

__device__ __forceinline__ float ssp(float x) {
    float sp = (x > 20.0f) ? x : log1pf(__expf(x));
    return sp - 0.6931471805599453f;
}

__global__ void k_embed(const int* __restrict__ z, const float* __restrict__ emb,
                        float* __restrict__ h) {
    int i = blockIdx.x * blockDim.x + threadIdx.x;
    int n = i >> 7, c = i & 127;
    h[i] = emb[z[n] * HID + c];
}

__global__ void k_hist(const int* __restrict__ ei, int* __restrict__ cnt) {
    int e = blockIdx.x * blockDim.x + threadIdx.x;
    if (e < N_EDGES) atomicAdd(&cnt[ei[e]], 1);
}

__global__ __launch_bounds__(1024) void k_scan(const int* __restrict__ cnt,
                                               int* __restrict__ rowptr,
                                               int* __restrict__ wo) {
    __shared__ int sums[1024];
    int t = threadIdx.x;
    int loc[16];
    int s = 0;
    #pragma unroll
    for (int i = 0; i < 16; ++i) { loc[i] = cnt[t * 16 + i]; s += loc[i]; }
    sums[t] = s;
    __syncthreads();
    for (int off = 1; off < 1024; off <<= 1) {
        int v = sums[t];
        int u = (t >= off) ? sums[t - off] : 0;
        __syncthreads();
        sums[t] = v + u;
        __syncthreads();
    }
    int ex = sums[t] - s;
    #pragma unroll
    for (int i = 0; i < 16; ++i) {
        rowptr[t * 16 + i] = ex;
        wo[t * 16 + i] = ex;
        ex += loc[i];
    }
    if (t == 1023) rowptr[16384] = ex;
}

// scatter into CSR order: meta.x = col, meta.y = ew bits
__global__ void k_scatter(const int* __restrict__ ei, const float* __restrict__ pos,
                          int* __restrict__ wo, int2* __restrict__ meta) {
    int e = blockIdx.x * blockDim.x + threadIdx.x;
    if (e >= N_EDGES) return;
    int r = ei[e], c = ei[N_EDGES + e];
    int p = atomicAdd(&wo[r], 1);
    float dx = pos[r * 3 + 0] - pos[c * 3 + 0];
    float dy = pos[r * 3 + 1] - pos[c * 3 + 1];
    float dz = pos[r * 3 + 2] - pos[c * 3 + 2];
    float ew = sqrtf(dx * dx + dy * dy + dz * dz);
    meta[p] = make_int2(c, __float_as_int(ew));
}

// Filter tables (flat [TROWS][FILT], includes cosine cutoff):
// ftab[layer][i][c] = (ssp(gauss(d_i)@W1+b1)@W2+b2)[c] * C(d_i)
__global__ __launch_bounds__(512) void k_tab(
    const float* __restrict__ mlp1_w, const float* __restrict__ mlp1_b,
    const float* __restrict__ mlp2_w, const float* __restrict__ mlp2_b,
    float* __restrict__ ftab)
{
    const int layer = blockIdx.x >> 5;
    const int tile  = blockIdx.x & 31;
    const float* W1 = mlp1_w + (size_t)layer * NG * FILT;
    const float* B1 = mlp1_b + (size_t)layer * FILT;
    const float* W2 = mlp2_w + (size_t)layer * FILT * FILT;
    const float* B2 = mlp2_b + (size_t)layer * FILT;
    float* out = ftab + (size_t)layer * TROWS * FILT + (size_t)tile * 64 * FILT;
    __shared__ float buf[FILT * 64];
    const int tid = threadIdx.x;
    const int e0 = (tid & 15) * 4;
    const int c0 = (tid >> 4) * 4;
    for (int idx = tid; idx < NG * 64; idx += 512) {
        int k = idx >> 6, e = idx & 63;
        float d = (float)(tile * 64 + e) * DSTEP;
        float dd = d - 0.2f * (float)k;
        buf[idx] = __expf(-12.5f * dd * dd);
    }
    __syncthreads();
    float acc[4][4];
    #pragma unroll
    for (int i = 0; i < 4; ++i)
        #pragma unroll
        for (int j = 0; j < 4; ++j) acc[i][j] = B1[c0 + j];
    for (int k = 0; k < NG; ++k) {
        float4 a = *(float4*)&buf[k * 64 + e0];
        float4 b = *(const float4*)&W1[k * FILT + c0];
        #pragma unroll
        for (int i = 0; i < 4; ++i)
            #pragma unroll
            for (int j = 0; j < 4; ++j)
                acc[i][j] += ((float*)&a)[i] * ((float*)&b)[j];
    }
    __syncthreads();
    #pragma unroll
    for (int j = 0; j < 4; ++j) {
        float4 w;
        ((float*)&w)[0] = ssp(acc[0][j]);
        ((float*)&w)[1] = ssp(acc[1][j]);
        ((float*)&w)[2] = ssp(acc[2][j]);
        ((float*)&w)[3] = ssp(acc[3][j]);
        *(float4*)&buf[(c0 + j) * 64 + e0] = w;
    }
    __syncthreads();
    float acc2[4][4];
    #pragma unroll
    for (int i = 0; i < 4; ++i)
        #pragma unroll
        for (int j = 0; j < 4; ++j) acc2[i][j] = B2[c0 + j];
    for (int k = 0; k < FILT; ++k) {
        float4 a = *(float4*)&buf[k * 64 + e0];
        float4 b = *(const float4*)&W2[k * FILT + c0];
        #pragma unroll
        for (int i = 0; i < 4; ++i)
            #pragma unroll
            for (int j = 0; j < 4; ++j)
                acc2[i][j] += ((float*)&a)[i] * ((float*)&b)[j];
    }
    #pragma unroll
    for (int i = 0; i < 4; ++i) {
        int r = tile * 64 + e0 + i;
        float d = (float)r * DSTEP;
        float C = 0.5f * (__cosf(d * 0.31415926535f) + 1.0f);
        #pragma unroll
        for (int j = 0; j < 4; ++j)
            out[(e0 + i) * FILT + c0 + j] = acc2[i][j] * C;
    }
}

// Wave-per-row edge aggregation with wave-interleaved row assignment.
// 8192 waves; wave w handles rows {w, w+8192}. No LDS, no barriers, no
// atomics -> waves retire independently (no straggler coupling).
// EUNROLL=4 keeps the load batch inside the VGPR budget at 8 blocks/CU.
__global__ __launch_bounds__(256, 8) void k_edge5(
    const int2* __restrict__ meta, const int* __restrict__ rowptr,
    const float* __restrict__ xh, const float* __restrict__ tab,
    float* __restrict__ agg)
{
    const int wid = blockIdx.x * 4 + (threadIdx.x >> 6);   // 0..8191
    const int lane = threadIdx.x & 63;
    const int c2 = lane * 2;
    for (int row = wid; row < N_NODES; row += 8192) {
        const int es = rowptr[row], ee = rowptr[row + 1];
        float ax = 0.f, ay = 0.f;
        for (int e = es; e < ee; e += EUNROLL) {
            float2 t0[EUNROLL], t1[EUNROLL], xv[EUNROLL];
            float f[EUNROLL], sc[EUNROLL];
            #pragma unroll
            for (int u = 0; u < EUNROLL; ++u) {
                int ec = min(e + u, ee - 1);
                sc[u] = (e + u < ee) ? 1.f : 0.f;
                int2 m = meta[ec];
                float d = __int_as_float(m.y);
                float uu = d * INV_DSTEP;
                int i0 = min((int)uu, TROWS - 2);
                f[u] = uu - (float)i0;
                t0[u] = *(const float2*)&tab[(size_t)i0 * FILT + c2];
                t1[u] = *(const float2*)&tab[(size_t)(i0 + 1) * FILT + c2];
                xv[u] = *(const float2*)&xh[(size_t)m.x * FILT + c2];
            }
            #pragma unroll
            for (int u = 0; u < EUNROLL; ++u) {
                float wx = fmaf(f[u], t1[u].x - t0[u].x, t0[u].x) * sc[u];
                float wy = fmaf(f[u], t1[u].y - t0[u].y, t0[u].y) * sc[u];
                ax = fmaf(wx, xv[u].x, ax);
                ay = fmaf(wy, xv[u].y, ay);
            }
        }
        *(float2*)&agg[(size_t)row * FILT + c2] = make_float2(ax, ay);
    }
}

// ---------------------------------------------------------------------------
// Wave-per-channel-group node GEMMs (unchanged from R7/R8).
// ---------------------------------------------------------------------------
__device__ __forceinline__ void stage_xt(const float* __restrict__ X, int n0,
                                         float* __restrict__ buf, int tid) {
    #pragma unroll
    for (int it = 0; it < 2; ++it) {
        int fi = tid + it * 1024;
        int node = fi & 63, kq = fi >> 6;
        float4 v = *(const float4*)&X[(size_t)(n0 + node) * 128 + kq * 4];
        buf[(4 * kq + 0) * 68 + node] = v.x;
        buf[(4 * kq + 1) * 68 + node] = v.y;
        buf[(4 * kq + 2) * 68 + node] = v.z;
        buf[(4 * kq + 3) * 68 + node] = v.w;
    }
}

__global__ __launch_bounds__(1024, 4) void k_gemm0(const float* __restrict__ X,
                                                   const float* __restrict__ W,
                                                   float* __restrict__ Y) {
    __shared__ float bufA[128 * 68];
    const int tid = threadIdx.x;
    const int lane = tid & 63;
    const int ch0 = __builtin_amdgcn_readfirstlane(tid >> 6) * 8;
    const int n0 = blockIdx.x * 64;
    stage_xt(X, n0, bufA, tid);
    __syncthreads();
    float acc[8];
    #pragma unroll
    for (int j = 0; j < 8; ++j) acc[j] = 0.f;
    #pragma unroll 4
    for (int k = 0; k < 128; ++k) {
        float a = bufA[k * 68 + lane];
        float4 w0 = *(const float4*)&W[k * 128 + ch0];
        float4 w1 = *(const float4*)&W[k * 128 + ch0 + 4];
        acc[0] = fmaf(a, w0.x, acc[0]); acc[1] = fmaf(a, w0.y, acc[1]);
        acc[2] = fmaf(a, w0.z, acc[2]); acc[3] = fmaf(a, w0.w, acc[3]);
        acc[4] = fmaf(a, w1.x, acc[4]); acc[5] = fmaf(a, w1.y, acc[5]);
        acc[6] = fmaf(a, w1.z, acc[6]); acc[7] = fmaf(a, w1.w, acc[7]);
    }
    size_t ro = (size_t)(n0 + lane) * 128 + ch0;
    *(float4*)&Y[ro]     = make_float4(acc[0], acc[1], acc[2], acc[3]);
    *(float4*)&Y[ro + 4] = make_float4(acc[4], acc[5], acc[6], acc[7]);
}

template<bool RESID, bool G3>
__global__ __launch_bounds__(1024, 4) void k_node3(
    const float* __restrict__ X,
    const float* __restrict__ W1, const float* __restrict__ B1,
    const float* __restrict__ W2, const float* __restrict__ B2,
    const float* __restrict__ Hin, float* __restrict__ Hout,
    const float* __restrict__ W3, float* __restrict__ XHout)
{
    __shared__ float bufA[128 * 68];
    __shared__ float bufB[128 * 68];
    const int tid = threadIdx.x;
    const int lane = tid & 63;
    const int ch0 = __builtin_amdgcn_readfirstlane(tid >> 6) * 8;
    const int n0 = blockIdx.x * 64;
    stage_xt(X, n0, bufA, tid);
    __syncthreads();
    float acc[8];
    #pragma unroll
    for (int j = 0; j < 8; ++j) acc[j] = B1[ch0 + j];
    #pragma unroll 4
    for (int k = 0; k < 128; ++k) {
        float a = bufA[k * 68 + lane];
        float4 w0 = *(const float4*)&W1[k * 128 + ch0];
        float4 w1 = *(const float4*)&W1[k * 128 + ch0 + 4];
        acc[0] = fmaf(a, w0.x, acc[0]); acc[1] = fmaf(a, w0.y, acc[1]);
        acc[2] = fmaf(a, w0.z, acc[2]); acc[3] = fmaf(a, w0.w, acc[3]);
        acc[4] = fmaf(a, w1.x, acc[4]); acc[5] = fmaf(a, w1.y, acc[5]);
        acc[6] = fmaf(a, w1.z, acc[6]); acc[7] = fmaf(a, w1.w, acc[7]);
    }
    #pragma unroll
    for (int j = 0; j < 8; ++j)
        bufB[(ch0 + j) * 68 + lane] = ssp(acc[j]);
    __syncthreads();
    float acc2[8];
    #pragma unroll
    for (int j = 0; j < 8; ++j) acc2[j] = B2[ch0 + j];
    #pragma unroll 4
    for (int k = 0; k < 128; ++k) {
        float a = bufB[k * 68 + lane];
        float4 w0 = *(const float4*)&W2[k * 128 + ch0];
        float4 w1 = *(const float4*)&W2[k * 128 + ch0 + 4];
        acc2[0] = fmaf(a, w0.x, acc2[0]); acc2[1] = fmaf(a, w0.y, acc2[1]);
        acc2[2] = fmaf(a, w0.z, acc2[2]); acc2[3] = fmaf(a, w0.w, acc2[3]);
        acc2[4] = fmaf(a, w1.x, acc2[4]); acc2[5] = fmaf(a, w1.y, acc2[5]);
        acc2[6] = fmaf(a, w1.z, acc2[6]); acc2[7] = fmaf(a, w1.w, acc2[7]);
    }
    size_t ro = (size_t)(n0 + lane) * 128 + ch0;
    if (RESID) {
        float4 h0 = *(const float4*)&Hin[ro];
        float4 h1 = *(const float4*)&Hin[ro + 4];
        acc2[0] += h0.x; acc2[1] += h0.y; acc2[2] += h0.z; acc2[3] += h0.w;
        acc2[4] += h1.x; acc2[5] += h1.y; acc2[6] += h1.z; acc2[7] += h1.w;
    }
    *(float4*)&Hout[ro]     = make_float4(acc2[0], acc2[1], acc2[2], acc2[3]);
    *(float4*)&Hout[ro + 4] = make_float4(acc2[4], acc2[5], acc2[6], acc2[7]);
    if (G3) {
        #pragma unroll
        for (int j = 0; j < 8; ++j)
            bufA[(ch0 + j) * 68 + lane] = acc2[j];
        __syncthreads();
        float acc3[8];
        #pragma unroll
        for (int j = 0; j < 8; ++j) acc3[j] = 0.f;
        #pragma unroll 4
        for (int k = 0; k < 128; ++k) {
            float a = bufA[k * 68 + lane];
            float4 w0 = *(const float4*)&W3[k * 128 + ch0];
            float4 w1 = *(const float4*)&W3[k * 128 + ch0 + 4];
            acc3[0] = fmaf(a, w0.x, acc3[0]); acc3[1] = fmaf(a, w0.y, acc3[1]);
            acc3[2] = fmaf(a, w0.z, acc3[2]); acc3[3] = fmaf(a, w0.w, acc3[3]);
            acc3[4] = fmaf(a, w1.x, acc3[4]); acc3[5] = fmaf(a, w1.y, acc3[5]);
            acc3[6] = fmaf(a, w1.z, acc3[6]); acc3[7] = fmaf(a, w1.w, acc3[7]);
        }
        *(float4*)&XHout[ro]     = make_float4(acc3[0], acc3[1], acc3[2], acc3[3]);
        *(float4*)&XHout[ro + 4] = make_float4(acc3[4], acc3[5], acc3[6], acc3[7]);
    }
}

// Partial-sum pooling using sortedness of batch.
__global__ __launch_bounds__(128) void k_pool2(const float* __restrict__ x,
                                               const int* __restrict__ batch,
                                               float* __restrict__ gsum) {
    const int c = threadIdx.x;
    const int n0 = blockIdx.x * 64;
    float acc = 0.f;
    int cur = batch[n0];
    for (int i = 0; i < 64; ++i) {
        int g = batch[n0 + i];
        float v = x[(size_t)(n0 + i) * 128 + c];
        if (g != cur) {
            atomicAdd(&gsum[cur * 128 + c], acc);
            acc = 0.f;
            cur = g;
        }
        acc += v;
    }
    atomicAdd(&gsum[cur * 128 + c], acc);
}

__global__ void k_div(const float* __restrict__ gsum, const int* __restrict__ batch,
                      float* __restrict__ out) {
    int g = blockIdx.x;
    int c = threadIdx.x;
    int a = 0, b = N_NODES;
    while (a < b) { int m = (a + b) >> 1; if (batch[m] < g) a = m + 1; else b = m; }
    int lo = a;
    b = N_NODES;
    while (a < b) { int m = (a + b) >> 1; if (batch[m] < g + 1) a = m + 1; else b = m; }
    int cnt = a - lo;
    out[g * 128 + c] = gsum[g * 128 + c] / fmaxf((float)cnt, 1.0f);
}

extern "C" void kernel_launch(void* const* d_in, const int* in_sizes, int n_in,
                              void* d_out, int out_size, void* d_ws, size_t ws_size,
                              hipStream_t stream) {
    const int*   z       = (const int*)  d_in[0];
    const float* pos     = (const float*)d_in[1];
    const int*   batch   = (const int*)  d_in[2];
    const int*   ei      = (const int*)  d_in[3];
    const float* emb     = (const float*)d_in[4];
    const float* mlp1_w  = (const float*)d_in[5];
    const float* mlp1_b  = (const float*)d_in[6];
    const float* mlp2_w  = (const float*)d_in[7];
    const float* mlp2_b  = (const float*)d_in[8];
    const float* cl1_w   = (const float*)d_in[9];
    const float* cl2_w   = (const float*)d_in[10];
    const float* cl2_b   = (const float*)d_in[11];
    const float* lin_w   = (const float*)d_in[12];
    const float* lin_b   = (const float*)d_in[13];
    const float* out1_w  = (const float*)d_in[14];
    const float* out1_b  = (const float*)d_in[15];
    const float* out2_w  = (const float*)d_in[16];
    const float* out2_b  = (const float*)d_in[17];

    float* ws     = (float*)d_ws;
    float* h      = ws;
    float* xh     = h    + (size_t)N_NODES * HID;
    float* agg    = xh   + (size_t)N_NODES * HID;
    int2*  meta   = (int2*)(agg + (size_t)N_NODES * HID);
    int*   cnt    = (int*)(meta + N_EDGES);
    int*   rowptr = cnt + N_NODES;
    int*   wo     = rowptr + N_NODES + 1;
    float* gsum   = (float*)(wo + N_NODES);            // 64*128
    float* ftab   = gsum + N_GRAPHS * 128;             // NL*TROWS*FILT floats

    hipMemsetAsync(cnt, 0, N_NODES * sizeof(int), stream);
    hipMemsetAsync(gsum, 0, N_GRAPHS * 128 * sizeof(float), stream);
    k_embed<<<N_NODES * HID / 256, 256, 0, stream>>>(z, emb, h);
    k_hist<<<N_EDGES / 256, 256, 0, stream>>>(ei, cnt);
    k_scan<<<1, 1024, 0, stream>>>(cnt, rowptr, wo);
    k_scatter<<<N_EDGES / 256, 256, 0, stream>>>(ei, pos, wo, meta);
    k_tab<<<NL * 32, 512, 0, stream>>>(mlp1_w, mlp1_b, mlp2_w, mlp2_b, ftab);

    k_gemm0<<<N_NODES / 64, 1024, 0, stream>>>(h, cl1_w, xh);
    for (int i = 0; i < NL; ++i) {
        k_edge5<<<2048, 256, 0, stream>>>(
            meta, rowptr, xh, ftab + (size_t)i * TROWS * FILT, agg);
        if (i < NL - 1) {
            k_node3<true, true><<<N_NODES / 64, 1024, 0, stream>>>(
                agg, cl2_w + (size_t)i * FILT * HID, cl2_b + (size_t)i * HID,
                lin_w + (size_t)i * HID * HID, lin_b + (size_t)i * HID,
                h, h, cl1_w + (size_t)(i + 1) * HID * FILT, xh);
        } else {
            k_node3<true, false><<<N_NODES / 64, 1024, 0, stream>>>(
                agg, cl2_w + (size_t)i * FILT * HID, cl2_b + (size_t)i * HID,
                lin_w + (size_t)i * HID * HID, lin_b + (size_t)i * HID,
                h, h, nullptr, nullptr);
        }
    }
    k_node3<false, false><<<N_NODES / 64, 1024, 0, stream>>>(
        h, out1_w, out1_b, out2_w, out2_b, nullptr, xh, nullptr, nullptr);
    k_pool2<<<N_NODES / 64, 128, 0, stream>>>(xh, batch, gsum);
    k_div<<<N_GRAPHS, 128, 0, stream>>>(gsum, batch, (float*)d_out);
}